// Round 1
// baseline (1943.027 us; speedup 1.0000x reference)
//
#include <hip/hip_runtime.h>
#include <math.h>

// ---------------------------------------------------------------------------
// Layouts:
//   Token order t = ((b*256 + g)*16 + l), g = yg*16+xg, l = yl*4+xl,
//   y = yg*4+yl, x = xg*4+xl  (window partition order). Features contiguous.
//   A1  : [65536][128]  activation (residual stream)
//   BUF : 134MB scratch reused as: xh (NHWC x) -> QKV1 -> H1 -> QKV2 -> H2 -> GX
//   LSTM state spatial-major: Hst/Cst [4096][128] (hw = y*64+x)
// ---------------------------------------------------------------------------

static __device__ __forceinline__ float geluf(float v) {
    return v * 0.5f * (1.0f + erff(v * 0.70710678118654752440f));
}

// ---------------- generic tiled fp32 GEMM ----------------------------------
// C[t][n] = sum_k A[t][k] * B[n][k] (+bias[n])
// mode 0: bias only; 1: gelu(bias+acc); 2: bias+acc+res (res may alias C)
// T, N multiples of 64; K multiple of 16. 256 threads, 64x64 tile, 4x4/thread.
__global__ __launch_bounds__(256) void gemm_k(
    const float* __restrict__ A, const float* __restrict__ B,
    const float* __restrict__ bias, float* __restrict__ C,
    const float* __restrict__ res, int N, int K, int mode)
{
    __shared__ float As[16][68];
    __shared__ float Bs[16][68];
    const int tid = threadIdx.x;
    const int tx = tid & 15, ty = tid >> 4;
    const int t0 = blockIdx.x * 64, n0 = blockIdx.y * 64;
    const int kk = tid & 15, rr = tid >> 4;
    float acc[4][4] = {};
    for (int k0 = 0; k0 < K; k0 += 16) {
#pragma unroll
        for (int p = 0; p < 4; ++p) {
            As[kk][rr + p*16] = A[(size_t)(t0 + rr + p*16) * K + (k0 + kk)];
            Bs[kk][rr + p*16] = B[(size_t)(n0 + rr + p*16) * K + (k0 + kk)];
        }
        __syncthreads();
#pragma unroll
        for (int q = 0; q < 16; ++q) {
            float4 av = *(const float4*)&As[q][ty*4];
            float4 bv = *(const float4*)&Bs[q][tx*4];
            float a[4] = {av.x, av.y, av.z, av.w};
            float b[4] = {bv.x, bv.y, bv.z, bv.w};
#pragma unroll
            for (int i = 0; i < 4; ++i)
#pragma unroll
                for (int j = 0; j < 4; ++j)
                    acc[i][j] = fmaf(a[i], b[j], acc[i][j]);
        }
        __syncthreads();
    }
#pragma unroll
    for (int i = 0; i < 4; ++i) {
        size_t off = (size_t)(t0 + ty*4 + i) * N + (n0 + tx*4);
        float vv[4];
#pragma unroll
        for (int j = 0; j < 4; ++j) {
            float v = acc[i][j];
            if (bias) v += bias[n0 + tx*4 + j];
            if (mode == 1) v = geluf(v);
            else if (mode == 2) v += res[off + j];
            vv[j] = v;
        }
        *(float4*)(C + off) = make_float4(vv[0], vv[1], vv[2], vv[3]);
    }
}

// ---------------- conv (2x2 stride 2) as GEMM over NHWC x ------------------
// A[t][k], k = (ky*2+kx)*128 + c -> XH[b][2y+ky][2x+kx][c]; B = packed Wc.
__global__ __launch_bounds__(256) void conv_gemm_k(
    const float* __restrict__ XH, const float* __restrict__ WC,
    const float* __restrict__ bias, float* __restrict__ C)
{
    __shared__ float As[16][68];
    __shared__ float Bs[16][68];
    const int tid = threadIdx.x;
    const int tx = tid & 15, ty = tid >> 4;
    const int t0 = blockIdx.x * 64, n0 = blockIdx.y * 64;
    const int kk = tid & 15, rr = tid >> 4;
    float acc[4][4] = {};
    for (int k0 = 0; k0 < 512; k0 += 16) {
        const int kq = k0 >> 7;               // constant within this k-chunk
        const int ky = kq >> 1, kx = kq & 1;
        const int c  = (k0 & 127) + kk;
#pragma unroll
        for (int p = 0; p < 4; ++p) {
            int row = t0 + rr + p*16;
            int b = row >> 12;
            int g = (row >> 4) & 255;
            int l = row & 15;
            int yy = ((g >> 4) << 2) | (l >> 2);
            int xx = ((g & 15) << 2) | (l & 3);
            size_t addr = (((size_t)(b*128 + 2*yy + ky) * 128) + (2*xx + kx)) * 128 + c;
            As[kk][rr + p*16] = XH[addr];
            Bs[kk][rr + p*16] = WC[(size_t)(n0 + rr + p*16) * 512 + (k0 + kk)];
        }
        __syncthreads();
#pragma unroll
        for (int q = 0; q < 16; ++q) {
            float4 av = *(const float4*)&As[q][ty*4];
            float4 bv = *(const float4*)&Bs[q][tx*4];
            float a[4] = {av.x, av.y, av.z, av.w};
            float b[4] = {bv.x, bv.y, bv.z, bv.w};
#pragma unroll
            for (int i = 0; i < 4; ++i)
#pragma unroll
                for (int j = 0; j < 4; ++j)
                    acc[i][j] = fmaf(a[i], b[j], acc[i][j]);
        }
        __syncthreads();
    }
#pragma unroll
    for (int i = 0; i < 4; ++i) {
        size_t off = (size_t)(t0 + ty*4 + i) * 128 + (n0 + tx*4);
        float vv[4];
#pragma unroll
        for (int j = 0; j < 4; ++j)
            vv[j] = acc[i][j] + bias[n0 + tx*4 + j];
        *(float4*)(C + off) = make_float4(vv[0], vv[1], vv[2], vv[3]);
    }
}

// ---------------- conv weight repack: [o][c][ky][kx] -> [o][(ky*2+kx)*128+c]
__global__ void repack_convw_k(const float* __restrict__ w, float* __restrict__ wc)
{
    int idx = blockIdx.x * 256 + threadIdx.x;   // 65536
    int o = idx >> 9, k = idx & 511;
    int kq = k >> 7, c = k & 127;
    wc[idx] = w[((o * 128 + c) << 2) + kq];
}

// ---------------- 2D transpose [R][S] -> [S][R], tiles of 32 ---------------
__global__ void transpose_k(const float* __restrict__ src, float* __restrict__ dst,
                            int R, int S, long sstride, long dstride)
{
    __shared__ float tile[32][33];
    const float* sp = src + (long)blockIdx.z * sstride;
    float* dp = dst + (long)blockIdx.z * dstride;
    int s0 = blockIdx.x * 32, r0 = blockIdx.y * 32;
    int tx = threadIdx.x, ty = threadIdx.y;  // (32,8)
#pragma unroll
    for (int i = 0; i < 4; ++i)
        tile[ty + i*8][tx] = sp[(size_t)(r0 + ty + i*8) * S + (s0 + tx)];
    __syncthreads();
#pragma unroll
    for (int i = 0; i < 4; ++i)
        dp[(size_t)(s0 + ty + i*8) * R + (r0 + tx)] = tile[tx][ty + i*8];
}

// ---------------- MSA1: windows of 16 tokens, 2 heads, hd=64 ---------------
// block: 8 windows x 2 heads x 16 rows = 256 threads. A1 += attn_out.
__global__ __launch_bounds__(256) void attn1_k(const float* __restrict__ QKV,
                                               float* __restrict__ A1)
{
    int bx = blockIdx.x;                 // 16 * 32
    int b = bx >> 5, g8 = bx & 31;
    int tid = threadIdx.x;
    int w = tid >> 5, h = (tid >> 4) & 1, r = tid & 15;
    int g = g8 * 8 + w;
    size_t tb = ((size_t)(b * 256 + g)) * 16;
    const float* qp = QKV + (tb + r) * 384 + h * 64;
    float qr[64];
#pragma unroll
    for (int d4 = 0; d4 < 16; ++d4) {
        float4 v = ((const float4*)qp)[d4];
        qr[4*d4] = v.x; qr[4*d4+1] = v.y; qr[4*d4+2] = v.z; qr[4*d4+3] = v.w;
    }
    float sc[16]; float mx = -1e30f;
#pragma unroll
    for (int k = 0; k < 16; ++k) {
        const float* kp = QKV + (tb + k) * 384 + 128 + h * 64;
        float s = 0.f;
#pragma unroll
        for (int d4 = 0; d4 < 16; ++d4) {
            float4 v = ((const float4*)kp)[d4];
            s = fmaf(qr[4*d4], v.x, s); s = fmaf(qr[4*d4+1], v.y, s);
            s = fmaf(qr[4*d4+2], v.z, s); s = fmaf(qr[4*d4+3], v.w, s);
        }
        s *= 0.08838834764831845f;      // 1/sqrt(128)
        sc[k] = s; mx = fmaxf(mx, s);
    }
    float sum = 0.f;
#pragma unroll
    for (int k = 0; k < 16; ++k) { sc[k] = expf(sc[k] - mx); sum += sc[k]; }
    float inv = 1.f / sum;
    float outv[64] = {};
#pragma unroll
    for (int k = 0; k < 16; ++k) {
        float p = sc[k] * inv;
        const float* vp = QKV + (tb + k) * 384 + 256 + h * 64;
#pragma unroll
        for (int d4 = 0; d4 < 16; ++d4) {
            float4 v = ((const float4*)vp)[d4];
            outv[4*d4]   = fmaf(p, v.x, outv[4*d4]);
            outv[4*d4+1] = fmaf(p, v.y, outv[4*d4+1]);
            outv[4*d4+2] = fmaf(p, v.z, outv[4*d4+2]);
            outv[4*d4+3] = fmaf(p, v.w, outv[4*d4+3]);
        }
    }
    float* dst = A1 + (tb + r) * 128 + h * 64;
#pragma unroll
    for (int d4 = 0; d4 < 16; ++d4) {
        float4 o = ((float4*)dst)[d4];
        o.x += outv[4*d4]; o.y += outv[4*d4+1]; o.z += outv[4*d4+2]; o.w += outv[4*d4+3];
        ((float4*)dst)[d4] = o;
    }
}

// ---------------- MSA2: attend over 256 windows, per (b,l,head) ------------
// block 256 threads = 256 q-rows; K/V staged in LDS as 2 chunks of 128,
// online softmax (per-key rescale). A1 += attn_out.
__global__ __launch_bounds__(256) void attn2_k(const float* __restrict__ QKV,
                                               float* __restrict__ A1)
{
    __shared__ float Ks[128 * 64];
    __shared__ float Vs[128 * 64];
    int bx = blockIdx.x;                     // 16*16*2
    int b = bx >> 5, l = (bx >> 1) & 15, h = bx & 1;
    int tid = threadIdx.x;
    size_t tq = ((size_t)(b * 256 + tid)) * 16 + l;
    const float* qp = QKV + tq * 384 + h * 64;
    float qr[64];
#pragma unroll
    for (int d4 = 0; d4 < 16; ++d4) {
        float4 v = ((const float4*)qp)[d4];
        qr[4*d4] = v.x; qr[4*d4+1] = v.y; qr[4*d4+2] = v.z; qr[4*d4+3] = v.w;
    }
    float outv[64] = {};
    float m = -1e30f, sum = 0.f;
    for (int ch = 0; ch < 2; ++ch) {
        __syncthreads();
        {   // stage 128 K rows + 128 V rows (each thread: half a row)
            int row = tid >> 1, half = tid & 1;
            size_t tk = ((size_t)(b * 256 + ch * 128 + row)) * 16 + l;
            const float* kp = QKV + tk * 384 + 128 + h * 64 + half * 32;
            const float* vp = kp + 128;
            float* kd = Ks + row * 64 + half * 32;
            float* vd = Vs + row * 64 + half * 32;
#pragma unroll
            for (int d4 = 0; d4 < 8; ++d4) {
                ((float4*)kd)[d4] = ((const float4*)kp)[d4];
                ((float4*)vd)[d4] = ((const float4*)vp)[d4];
            }
        }
        __syncthreads();
        for (int k = 0; k < 128; ++k) {
            const float4* krow = (const float4*)(Ks + k * 64);
            float s = 0.f;
#pragma unroll
            for (int d4 = 0; d4 < 16; ++d4) {
                float4 kv = krow[d4];
                s = fmaf(qr[4*d4], kv.x, s); s = fmaf(qr[4*d4+1], kv.y, s);
                s = fmaf(qr[4*d4+2], kv.z, s); s = fmaf(qr[4*d4+3], kv.w, s);
            }
            s *= 0.08838834764831845f;
            float nm = fmaxf(m, s);
            float corr = expf(m - nm);       // 0 when m = -1e30
            float p = expf(s - nm);
            sum = sum * corr + p;
            const float4* vrow = (const float4*)(Vs + k * 64);
#pragma unroll
            for (int d4 = 0; d4 < 16; ++d4) {
                float4 vv = vrow[d4];
                outv[4*d4]   = fmaf(p, vv.x, outv[4*d4]   * corr);
                outv[4*d4+1] = fmaf(p, vv.y, outv[4*d4+1] * corr);
                outv[4*d4+2] = fmaf(p, vv.z, outv[4*d4+2] * corr);
                outv[4*d4+3] = fmaf(p, vv.w, outv[4*d4+3] * corr);
            }
            m = nm;
        }
    }
    float inv = 1.f / sum;
    float* dst = A1 + tq * 128 + h * 64;
#pragma unroll
    for (int d4 = 0; d4 < 16; ++d4) {
        float4 o = ((float4*)dst)[d4];
        o.x += outv[4*d4] * inv;   o.y += outv[4*d4+1] * inv;
        o.z += outv[4*d4+2] * inv; o.w += outv[4*d4+3] * inv;
        ((float4*)dst)[d4] = o;
    }
}

// ---------------- ConvLSTM gate step ---------------------------------------
// gates[hw][512] = GX[t(hw)][512] + GH[hw][512]; f,i,o: softmax over their
// 128 channels; s: tanh. Cn = f*C + i*s; hn = o*tanh(Cn).
// One wave per spatial row; 16-lane groups hold one 128-ch gate each.
__global__ __launch_bounds__(256) void lstm_gate_k(
    const float* __restrict__ GX, const float* __restrict__ GHp,
    float* __restrict__ Hst, float* __restrict__ Cst,
    float* __restrict__ hsb, int bstep)
{
    int row  = blockIdx.x * 4 + (threadIdx.x >> 6);
    int lane = threadIdx.x & 63;
    int y = row >> 6, x = row & 63;
    int g = ((y >> 2) << 4) | (x >> 2);
    int l = ((y & 3) << 2) | (x & 3);
    size_t t = ((size_t)(bstep * 256 + g)) * 16 + l;
    const float* gx = GX  + t * 512 + lane * 8;
    const float* gh = GHp + (size_t)row * 512 + lane * 8;
    float v[8];
    {
        float4 a0 = ((const float4*)gx)[0], a1 = ((const float4*)gx)[1];
        float4 b0 = ((const float4*)gh)[0], b1 = ((const float4*)gh)[1];
        v[0]=a0.x+b0.x; v[1]=a0.y+b0.y; v[2]=a0.z+b0.z; v[3]=a0.w+b0.w;
        v[4]=a1.x+b1.x; v[5]=a1.y+b1.y; v[6]=a1.z+b1.z; v[7]=a1.w+b1.w;
    }
    int seg = lane >> 4;                 // 0=f 1=i 2=s 3=o
    // group softmax (harmless for seg 2, discarded)
    float mx = v[0];
#pragma unroll
    for (int j = 1; j < 8; ++j) mx = fmaxf(mx, v[j]);
#pragma unroll
    for (int msk = 1; msk < 16; msk <<= 1) mx = fmaxf(mx, __shfl_xor(mx, msk));
    float e[8]; float ssum = 0.f;
#pragma unroll
    for (int j = 0; j < 8; ++j) { e[j] = expf(v[j] - mx); ssum += e[j]; }
#pragma unroll
    for (int msk = 1; msk < 16; msk <<= 1) ssum += __shfl_xor(ssum, msk);
    float invs = 1.f / ssum;
    float gv[8];
#pragma unroll
    for (int j = 0; j < 8; ++j) gv[j] = (seg == 2) ? tanhf(v[j]) : e[j] * invs;
    // gather f,i,s,o per channel (channels c = q*8+j live on lanes q,16+q,32+q,48+q)
    int q = lane & 15;
    float fv[8], iv[8], sv[8], ov[8];
#pragma unroll
    for (int j = 0; j < 8; ++j) {
        fv[j] = __shfl(gv[j], q);
        iv[j] = __shfl(gv[j], 16 + q);
        sv[j] = __shfl(gv[j], 32 + q);
        ov[j] = __shfl(gv[j], 48 + q);
    }
    if (lane < 16) {
        size_t cb = (size_t)row * 128 + lane * 8;
        float4 c0 = *(float4*)(Cst + cb); float4 c1 = *(float4*)(Cst + cb + 4);
        float cp[8] = {c0.x,c0.y,c0.z,c0.w,c1.x,c1.y,c1.z,c1.w};
        float cn[8], hn[8];
#pragma unroll
        for (int j = 0; j < 8; ++j) {
            cn[j] = fmaf(fv[j], cp[j], iv[j] * sv[j]);
            hn[j] = ov[j] * tanhf(cn[j]);
        }
        *(float4*)(Cst + cb)     = make_float4(cn[0],cn[1],cn[2],cn[3]);
        *(float4*)(Cst + cb + 4) = make_float4(cn[4],cn[5],cn[6],cn[7]);
        *(float4*)(Hst + cb)     = make_float4(hn[0],hn[1],hn[2],hn[3]);
        *(float4*)(Hst + cb + 4) = make_float4(hn[4],hn[5],hn[6],hn[7]);
        *(float4*)(hsb + cb)     = make_float4(hn[0],hn[1],hn[2],hn[3]);
        *(float4*)(hsb + cb + 4) = make_float4(hn[4],hn[5],hn[6],hn[7]);
    }
}

// ---------------------------------------------------------------------------
extern "C" void kernel_launch(void* const* d_in, const int* in_sizes, int n_in,
                              void* d_out, int out_size, void* d_ws, size_t ws_size,
                              hipStream_t stream)
{
    const float* x      = (const float*)d_in[0];
    const float* h0     = (const float*)d_in[1];
    const float* c0     = (const float*)d_in[2];
    const float* conv_w = (const float*)d_in[3];
    const float* conv_b = (const float*)d_in[4];
    const float* qkv1_w = (const float*)d_in[5];
    const float* qkv1_b = (const float*)d_in[6];
    const float* m1w1   = (const float*)d_in[7];
    const float* m1b1   = (const float*)d_in[8];
    const float* m1w2   = (const float*)d_in[9];
    const float* m1b2   = (const float*)d_in[10];
    const float* qkv2_w = (const float*)d_in[11];
    const float* qkv2_b = (const float*)d_in[12];
    const float* m2w1   = (const float*)d_in[13];
    const float* m2b1   = (const float*)d_in[14];
    const float* m2w2   = (const float*)d_in[15];
    const float* m2b2   = (const float*)d_in[16];
    const float* wx     = (const float*)d_in[17];
    const float* wh     = (const float*)d_in[18];
    const float* bh     = (const float*)d_in[19];
    float* out = (float*)d_out;

    char* ws = (char*)d_ws;
    float* BUF = (float*)(ws);                       // 134,217,728 B
    float* A1  = (float*)(ws + 134217728);           //  33,554,432 B
    float* HSW = (float*)(ws + 167772160);           //  33,554,432 B
    float* Hst = (float*)(ws + 201326592);           //   2,097,152 B
    float* Cst = (float*)(ws + 203423744);           //   2,097,152 B
    float* GH  = (float*)(ws + 205520896);           //   8,388,608 B
    float* WC  = (float*)(ws + 213909504);           //     262,144 B

    // conv weight repack + x NCHW->NHWC (into BUF as xh)
    repack_convw_k<<<256, 256, 0, stream>>>(conv_w, WC);
    transpose_k<<<dim3(512, 4, 16), dim3(32, 8), 0, stream>>>(
        x, BUF, 128, 16384, 128L * 16384, 16384L * 128);
    // conv as GEMM -> A1 (window-partition token order)
    conv_gemm_k<<<dim3(1024, 2), 256, 0, stream>>>(BUF, WC, conv_b, A1);

    // block 1: local MSA + MLP
    gemm_k<<<dim3(1024, 6), 256, 0, stream>>>(A1, qkv1_w, qkv1_b, BUF, nullptr, 384, 128, 0);
    attn1_k<<<512, 256, 0, stream>>>(BUF, A1);
    gemm_k<<<dim3(1024, 8), 256, 0, stream>>>(A1, m1w1, m1b1, BUF, nullptr, 512, 128, 1);
    gemm_k<<<dim3(1024, 2), 256, 0, stream>>>(BUF, m1w2, m1b2, A1, A1, 128, 512, 2);

    // block 2: dilated MSA + MLP
    gemm_k<<<dim3(1024, 6), 256, 0, stream>>>(A1, qkv2_w, qkv2_b, BUF, nullptr, 384, 128, 0);
    attn2_k<<<512, 256, 0, stream>>>(BUF, A1);
    gemm_k<<<dim3(1024, 8), 256, 0, stream>>>(A1, m2w1, m2b1, BUF, nullptr, 512, 128, 1);
    gemm_k<<<dim3(1024, 2), 256, 0, stream>>>(BUF, m2w2, m2b2, A1, A1, 128, 512, 2);

    // LSTM: precompute GX = Wx@x + bh for all steps (token order), states to [hw][c]
    gemm_k<<<dim3(1024, 8), 256, 0, stream>>>(A1, wx, bh, BUF, nullptr, 512, 128, 0);
    transpose_k<<<dim3(128, 4, 1), dim3(32, 8), 0, stream>>>(h0, Hst, 128, 4096, 0, 0);
    transpose_k<<<dim3(128, 4, 1), dim3(32, 8), 0, stream>>>(c0, Cst, 128, 4096, 0, 0);

    for (int s = 0; s < 16; ++s) {
        gemm_k<<<dim3(64, 8), 256, 0, stream>>>(Hst, wh, nullptr, GH, nullptr, 512, 128, 0);
        lstm_gate_k<<<1024, 256, 0, stream>>>(BUF, GH, Hst, Cst, HSW + (size_t)s * 524288, s);
    }

    // outputs: hs (16,128,64,64), hf, Cf
    transpose_k<<<dim3(4, 128, 16), dim3(32, 8), 0, stream>>>(HSW, out, 4096, 128, 524288, 524288);
    transpose_k<<<dim3(4, 128, 1), dim3(32, 8), 0, stream>>>(Hst, out + 8388608, 4096, 128, 0, 0);
    transpose_k<<<dim3(4, 128, 1), dim3(32, 8), 0, stream>>>(Cst, out + 8912896, 4096, 128, 0, 0);
}

// Round 2
// 1453.564 us; speedup vs baseline: 1.3367x; 1.3367x over previous
//
#include <hip/hip_runtime.h>
#include <math.h>

typedef unsigned short u16;
typedef unsigned int   u32;
typedef __attribute__((ext_vector_type(8))) short s16x8;   // 8 bf16 (4 VGPR)
typedef __attribute__((ext_vector_type(4))) float f32x4;

// ---------------- helpers ---------------------------------------------------
__device__ __forceinline__ u16 f2bf(float f) {
    union { float f; u32 u; } a; a.f = f;
    return (u16)((a.u + 0x7fffu + ((a.u >> 16) & 1u)) >> 16);
}
__device__ __forceinline__ float bf2f(u16 h) {
    union { u32 u; float f; } a; a.u = ((u32)h) << 16; return a.f;
}
__device__ __forceinline__ float bflo(u32 u){ union{u32 i;float f;} a; a.i = u<<16; return a.f; }
__device__ __forceinline__ float bfhi(u32 u){ union{u32 i;float f;} a; a.i = u & 0xffff0000u; return a.f; }

__device__ __forceinline__ float tanh_fast(float x) {
    float xc = fminf(fmaxf(x, -15.f), 15.f);
    float e = __expf(2.f * xc);
    return (e - 1.f) * __frcp_rn(e + 1.f);
}
__device__ __forceinline__ float erf_fast(float x) {
    float ax = fabsf(x);
    float t = __frcp_rn(fmaf(0.3275911f, ax, 1.f));
    float poly = t*(0.254829592f + t*(-0.284496736f + t*(1.421413741f +
                 t*(-1.453152027f + t*1.061405429f))));
    float y = 1.f - poly * __expf(-ax*ax);
    return copysignf(y, x);
}
__device__ __forceinline__ float gelu_fast(float v) {
    return v * 0.5f * (1.f + erf_fast(v * 0.70710678118654752440f));
}

__device__ __forceinline__ void gload16(const void* g, void* l) {
    __builtin_amdgcn_global_load_lds(
        (const __attribute__((address_space(1))) void*)g,
        (__attribute__((address_space(3))) void*)l, 16, 0, 0);
}

// ---------------- bf16 MFMA GEMM: C[t][n] = sum_k A[t][k]*B[n][k] ----------
// 128x128 tile, BK=64, 4 waves. flags: 1 gelu, 2 res f32, 4 write Cf,
// 8 write Cb (bf16), 16 res bf16.
__global__ __launch_bounds__(256) void gemm_bf16_k(
    const u16* __restrict__ A, const u16* __restrict__ B,
    const float* __restrict__ bias, float* __restrict__ Cf,
    u16* __restrict__ Cb, const void* __restrict__ Res,
    int N, int K, int flags)
{
    __shared__ u16 As[128 * 64];
    __shared__ u16 Bs[128 * 64];
    const int tid = threadIdx.x;
    const int w = tid >> 6, lane = tid & 63;
    const int wr = w >> 1, wc = w & 1;
    const int t0 = blockIdx.x * 128, n0 = blockIdx.y * 128;
    const int ns = K >> 6;
    const int rsub = lane >> 3, ssub = lane & 7;

    f32x4 acc[4][4];
#pragma unroll
    for (int m = 0; m < 4; ++m)
#pragma unroll
        for (int n = 0; n < 4; ++n) acc[m][n] = (f32x4){0.f,0.f,0.f,0.f};

    const u16* Abase = A + (size_t)t0 * K;
    const u16* Bbase = B + (size_t)n0 * K;

    for (int s = 0; s < ns; ++s) {
        // stage A and B tiles: linear LDS dest, source pre-swizzled
#pragma unroll
        for (int r = 0; r < 4; ++r) {
            int row = r*32 + w*8 + rsub;
            int c16 = ssub ^ (row & 7);
            gload16(Abase + (size_t)row * K + s*64 + c16*8, As + (r*32 + w*8)*64);
        }
#pragma unroll
        for (int r = 0; r < 4; ++r) {
            int row = r*32 + w*8 + rsub;
            int c16 = ssub ^ (row & 7);
            gload16(Bbase + (size_t)row * K + s*64 + c16*8, Bs + (r*32 + w*8)*64);
        }
        __syncthreads();   // drains vmcnt: tiles resident

#pragma unroll
        for (int kk = 0; kk < 2; ++kk) {
            s16x8 av[4], bv[4];
#pragma unroll
            for (int m = 0; m < 4; ++m) {
                int ra = wr*64 + m*16 + (lane & 15);
                int ca = (kk*4 + (lane >> 4)) ^ (ra & 7);
                av[m] = *(const s16x8*)&As[ra*64 + ca*8];
                int rb = wc*64 + m*16 + (lane & 15);
                int cb2 = (kk*4 + (lane >> 4)) ^ (rb & 7);
                bv[m] = *(const s16x8*)&Bs[rb*64 + cb2*8];
            }
#pragma unroll
            for (int m = 0; m < 4; ++m)
#pragma unroll
                for (int n = 0; n < 4; ++n)
                    acc[m][n] = __builtin_amdgcn_mfma_f32_16x16x32_bf16(
                        av[m], bv[n], acc[m][n], 0, 0, 0);
        }
        __syncthreads();   // all reads done before next overwrite
    }

    // epilogue
#pragma unroll
    for (int n = 0; n < 4; ++n) {
        int col = n0 + wc*64 + n*16 + (lane & 15);
        float bv = bias ? bias[col] : 0.f;
#pragma unroll
        for (int m = 0; m < 4; ++m) {
            int row0 = t0 + wr*64 + m*16 + (lane >> 4)*4;
#pragma unroll
            for (int j = 0; j < 4; ++j) {
                size_t off = (size_t)(row0 + j) * N + col;
                float v = acc[m][n][j] + bv;
                if (flags & 1)  v = gelu_fast(v);
                if (flags & 2)  v += ((const float*)Res)[off];
                if (flags & 16) v += bf2f(((const u16*)Res)[off]);
                if (flags & 4)  Cf[off] = v;
                if (flags & 8)  Cb[off] = f2bf(v);
            }
        }
    }
}

// ---------------- XA builder: x NCHW -> token-order [65536][512] bf16 ------
// k = (ky*2+kx)*128 + c
__global__ __launch_bounds__(256) void xa_build_k(const float* __restrict__ x,
                                                  u16* __restrict__ XA)
{
    __shared__ float tile[32][2][129];
    const int y = blockIdx.x, cc = blockIdx.y, b = blockIdx.z;
    const int tid = threadIdx.x;
    {
        int c_i = tid >> 3, rem = tid & 7;
        int yy = rem >> 2, qx = rem & 3;
        const float* p = x + (((size_t)(b*128 + cc*32 + c_i) * 128) + (2*y + yy)) * 128 + qx*32;
#pragma unroll
        for (int e = 0; e < 8; ++e) {
            float4 v = ((const float4*)p)[e];
            tile[c_i][yy][qx*32 + e*4 + 0] = v.x;
            tile[c_i][yy][qx*32 + e*4 + 1] = v.y;
            tile[c_i][yy][qx*32 + e*4 + 2] = v.z;
            tile[c_i][yy][qx*32 + e*4 + 3] = v.w;
        }
    }
    __syncthreads();
    {
        int xo = tid >> 2, kq = tid & 3;
        int ky = kq >> 1, kx = kq & 1;
        size_t t = (size_t)b*4096 + ((y>>2)*16 + (xo>>2))*16 + (y&3)*4 + (xo&3);
        u16* dst = XA + t*512 + kq*128 + cc*32;
        u32 pk[16];
#pragma unroll
        for (int e = 0; e < 16; ++e) {
            float v0 = tile[2*e  ][ky][2*xo + kx];
            float v1 = tile[2*e+1][ky][2*xo + kx];
            pk[e] = (u32)f2bf(v0) | ((u32)f2bf(v1) << 16);
        }
#pragma unroll
        for (int e = 0; e < 4; ++e)
            ((uint4*)dst)[e] = make_uint4(pk[4*e], pk[4*e+1], pk[4*e+2], pk[4*e+3]);
    }
}

// ---------------- weight convert (all weights -> one bf16 region) ----------
__global__ void conv_weights_k(const float* __restrict__ conv_w, const float* __restrict__ qkv1_w,
    const float* __restrict__ m1w1, const float* __restrict__ m1w2,
    const float* __restrict__ qkv2_w, const float* __restrict__ m2w1,
    const float* __restrict__ m2w2, const float* __restrict__ wx,
    const float* __restrict__ wh, u16* __restrict__ Wb)
{
    int idx = blockIdx.x * 256 + threadIdx.x;
    if (idx >= 557056) return;
    float v;
    if (idx < 65536) { int o = idx >> 9, k = idx & 511; v = conv_w[((o*128 + (k & 127)) << 2) + (k >> 7)]; }
    else if (idx < 114688) v = qkv1_w[idx - 65536];
    else if (idx < 180224) v = m1w1[idx - 114688];
    else if (idx < 245760) v = m1w2[idx - 180224];
    else if (idx < 294912) v = qkv2_w[idx - 245760];
    else if (idx < 360448) v = m2w1[idx - 294912];
    else if (idx < 425984) v = m2w2[idx - 360448];
    else if (idx < 491520) v = wx[idx - 425984];
    else v = wh[idx - 491520];
    Wb[idx] = f2bf(v);
}

// ---------------- MSA1 (bf16 QKV in, A1f += out, A1b refreshed) -----------
__global__ __launch_bounds__(256) void attn1_k(const u16* __restrict__ QKV,
                                               float* __restrict__ A1f,
                                               u16* __restrict__ A1b)
{
    int bx = blockIdx.x;                 // 512
    int b = bx >> 5, g8 = bx & 31;
    int tid = threadIdx.x;
    int w = tid >> 5, h = (tid >> 4) & 1, r = tid & 15;
    int g = g8*8 + w;
    size_t tb = ((size_t)(b*256 + g)) * 16;
    float qr[64];
    {
        const uint4* qp = (const uint4*)(QKV + (tb + r)*384 + h*64);
#pragma unroll
        for (int i = 0; i < 8; ++i) {
            uint4 u = qp[i];
            qr[8*i+0]=bflo(u.x); qr[8*i+1]=bfhi(u.x); qr[8*i+2]=bflo(u.y); qr[8*i+3]=bfhi(u.y);
            qr[8*i+4]=bflo(u.z); qr[8*i+5]=bfhi(u.z); qr[8*i+6]=bflo(u.w); qr[8*i+7]=bfhi(u.w);
        }
    }
    float sc[16]; float mx = -1e30f;
#pragma unroll
    for (int k = 0; k < 16; ++k) {
        const uint4* kp = (const uint4*)(QKV + (tb + k)*384 + 128 + h*64);
        float s = 0.f;
#pragma unroll
        for (int i = 0; i < 8; ++i) {
            uint4 u = kp[i];
            s = fmaf(qr[8*i+0], bflo(u.x), s); s = fmaf(qr[8*i+1], bfhi(u.x), s);
            s = fmaf(qr[8*i+2], bflo(u.y), s); s = fmaf(qr[8*i+3], bfhi(u.y), s);
            s = fmaf(qr[8*i+4], bflo(u.z), s); s = fmaf(qr[8*i+5], bfhi(u.z), s);
            s = fmaf(qr[8*i+6], bflo(u.w), s); s = fmaf(qr[8*i+7], bfhi(u.w), s);
        }
        sc[k] = s * 0.08838834764831845f;
        mx = fmaxf(mx, sc[k]);
    }
    float sum = 0.f;
#pragma unroll
    for (int k = 0; k < 16; ++k) { sc[k] = __expf(sc[k] - mx); sum += sc[k]; }
    float inv = __frcp_rn(sum);
    float outv[64] = {};
#pragma unroll
    for (int k = 0; k < 16; ++k) {
        float p = sc[k] * inv;
        const uint4* vp = (const uint4*)(QKV + (tb + k)*384 + 256 + h*64);
#pragma unroll
        for (int i = 0; i < 8; ++i) {
            uint4 u = vp[i];
            outv[8*i+0] = fmaf(p, bflo(u.x), outv[8*i+0]); outv[8*i+1] = fmaf(p, bfhi(u.x), outv[8*i+1]);
            outv[8*i+2] = fmaf(p, bflo(u.y), outv[8*i+2]); outv[8*i+3] = fmaf(p, bfhi(u.y), outv[8*i+3]);
            outv[8*i+4] = fmaf(p, bflo(u.z), outv[8*i+4]); outv[8*i+5] = fmaf(p, bfhi(u.z), outv[8*i+5]);
            outv[8*i+6] = fmaf(p, bflo(u.w), outv[8*i+6]); outv[8*i+7] = fmaf(p, bfhi(u.w), outv[8*i+7]);
        }
    }
    float* dst = A1f + (tb + r)*128 + h*64;
    u16*  dstb = A1b + (tb + r)*128 + h*64;
#pragma unroll
    for (int i = 0; i < 16; ++i) {
        float4 o = ((float4*)dst)[i];
        o.x += outv[4*i]; o.y += outv[4*i+1]; o.z += outv[4*i+2]; o.w += outv[4*i+3];
        ((float4*)dst)[i] = o;
        u32 p0 = (u32)f2bf(o.x) | ((u32)f2bf(o.y) << 16);
        u32 p1 = (u32)f2bf(o.z) | ((u32)f2bf(o.w) << 16);
        ((uint2*)dstb)[i] = make_uint2(p0, p1);
    }
}

// ---------------- MSA2: 256 windows, chunked LDS + tile-rescale ------------
__global__ __launch_bounds__(256) void attn2_k(const u16* __restrict__ QKV,
                                               float* __restrict__ A1f,
                                               u16* __restrict__ A1b)
{
    __shared__ float Ks[64][68];
    __shared__ float Vs[64][68];
    int bx = blockIdx.x;                 // 512
    int b = bx >> 5, l = (bx >> 1) & 15, h = bx & 1;
    int tid = threadIdx.x;
    size_t tq = ((size_t)(b*256 + tid))*16 + l;
    float qr[64];
    {
        const uint4* qp = (const uint4*)(QKV + tq*384 + h*64);
#pragma unroll
        for (int i = 0; i < 8; ++i) {
            uint4 u = qp[i];
            qr[8*i+0]=bflo(u.x); qr[8*i+1]=bfhi(u.x); qr[8*i+2]=bflo(u.y); qr[8*i+3]=bfhi(u.y);
            qr[8*i+4]=bflo(u.z); qr[8*i+5]=bfhi(u.z); qr[8*i+6]=bflo(u.w); qr[8*i+7]=bfhi(u.w);
        }
    }
    float outv[64] = {};
    float m = -1e30f, sum = 0.f;
    for (int ch = 0; ch < 4; ++ch) {
        __syncthreads();
        {   // stage 64 K rows + 64 V rows (bf16 -> f32)
            int row = tid & 63, part = tid >> 6;       // part: 16 cols
            size_t tk = ((size_t)(b*256 + ch*64 + row))*16 + l;
            const uint4* kp = (const uint4*)(QKV + tk*384 + 128 + h*64 + part*16);
            const uint4* vp = (const uint4*)(QKV + tk*384 + 256 + h*64 + part*16);
#pragma unroll
            for (int q2 = 0; q2 < 2; ++q2) {
                uint4 u = kp[q2];
                float4* kd = (float4*)&Ks[row][part*16 + q2*8];
                kd[0] = make_float4(bflo(u.x), bfhi(u.x), bflo(u.y), bfhi(u.y));
                kd[1] = make_float4(bflo(u.z), bfhi(u.z), bflo(u.w), bfhi(u.w));
                uint4 v = vp[q2];
                float4* vd = (float4*)&Vs[row][part*16 + q2*8];
                vd[0] = make_float4(bflo(v.x), bfhi(v.x), bflo(v.y), bfhi(v.y));
                vd[1] = make_float4(bflo(v.z), bfhi(v.z), bflo(v.w), bfhi(v.w));
            }
        }
        __syncthreads();
        for (int sub = 0; sub < 4; ++sub) {
            float sc[16]; float smax = -1e30f;
#pragma unroll
            for (int k2 = 0; k2 < 16; ++k2) {
                const float* kr = &Ks[sub*16 + k2][0];
                float s = 0.f;
#pragma unroll
                for (int d = 0; d < 16; ++d) {
                    float4 kv = ((const float4*)kr)[d];
                    s = fmaf(qr[4*d],   kv.x, s); s = fmaf(qr[4*d+1], kv.y, s);
                    s = fmaf(qr[4*d+2], kv.z, s); s = fmaf(qr[4*d+3], kv.w, s);
                }
                sc[k2] = s * 0.08838834764831845f;
                smax = fmaxf(smax, sc[k2]);
            }
            float nm = fmaxf(m, smax);
            float corr = __expf(m - nm);
            sum *= corr;
#pragma unroll
            for (int d = 0; d < 64; ++d) outv[d] *= corr;
            m = nm;
#pragma unroll
            for (int k2 = 0; k2 < 16; ++k2) {
                float p = __expf(sc[k2] - m);
                sum += p;
                const float* vr = &Vs[sub*16 + k2][0];
#pragma unroll
                for (int d = 0; d < 16; ++d) {
                    float4 vv = ((const float4*)vr)[d];
                    outv[4*d]   = fmaf(p, vv.x, outv[4*d]);
                    outv[4*d+1] = fmaf(p, vv.y, outv[4*d+1]);
                    outv[4*d+2] = fmaf(p, vv.z, outv[4*d+2]);
                    outv[4*d+3] = fmaf(p, vv.w, outv[4*d+3]);
                }
            }
        }
    }
    float inv = __frcp_rn(sum);
    float* dst = A1f + tq*128 + h*64;
    u16*  dstb = A1b + tq*128 + h*64;
#pragma unroll
    for (int i = 0; i < 16; ++i) {
        float4 o = ((float4*)dst)[i];
        o.x += outv[4*i] * inv;   o.y += outv[4*i+1] * inv;
        o.z += outv[4*i+2] * inv; o.w += outv[4*i+3] * inv;
        ((float4*)dst)[i] = o;
        u32 p0 = (u32)f2bf(o.x) | ((u32)f2bf(o.y) << 16);
        u32 p1 = (u32)f2bf(o.z) | ((u32)f2bf(o.w) << 16);
        ((uint2*)dstb)[i] = make_uint2(p0, p1);
    }
}

// ---------------- LSTM init: h0/c0 NCHW -> token-order states --------------
__global__ void lstm_init_k(const float* __restrict__ h0, const float* __restrict__ c0,
                            u16* __restrict__ Hstb, float* __restrict__ Cst)
{
    int idx = blockIdx.x * 256 + threadIdx.x;     // 32768
    int t = idx >> 3, q = idx & 7;
    int g = t >> 4, l = t & 15;
    int y = (g >> 4)*4 + (l >> 2);
    int x = (g & 15)*4 + (l & 3);
    int hw = y*64 + x;
    u32 pk[8]; float cs[16];
#pragma unroll
    for (int e = 0; e < 16; ++e) {
        int c = q*16 + e;
        float hv = h0[(size_t)c*4096 + hw];
        cs[e] = c0[(size_t)c*4096 + hw];
        if (e & 1) pk[e>>1] |= ((u32)f2bf(hv)) << 16;
        else       pk[e>>1]  = (u32)f2bf(hv);
    }
    u16* hd = Hstb + (size_t)t*128 + q*16;
    ((uint4*)hd)[0] = make_uint4(pk[0], pk[1], pk[2], pk[3]);
    ((uint4*)hd)[1] = make_uint4(pk[4], pk[5], pk[6], pk[7]);
    float* cd = Cst + (size_t)t*128 + q*16;
#pragma unroll
    for (int e = 0; e < 4; ++e)
        ((float4*)cd)[e] = make_float4(cs[4*e], cs[4*e+1], cs[4*e+2], cs[4*e+3]);
}

// ---------------- ConvLSTM gate step (token order) -------------------------
__global__ __launch_bounds__(256) void lstm_gate_k(
    const float* __restrict__ gates, float* __restrict__ Cst,
    u16* __restrict__ Hstb, float* __restrict__ hs_s)
{
    int t = blockIdx.x * 4 + (threadIdx.x >> 6);
    int lane = threadIdx.x & 63;
    const float* gp = gates + (size_t)t*512 + lane*8;
    float v[8];
    {
        float4 a0 = ((const float4*)gp)[0], a1 = ((const float4*)gp)[1];
        v[0]=a0.x; v[1]=a0.y; v[2]=a0.z; v[3]=a0.w;
        v[4]=a1.x; v[5]=a1.y; v[6]=a1.z; v[7]=a1.w;
    }
    int seg = lane >> 4;                 // 0=f 1=i 2=s 3=o
    float mx = v[0];
#pragma unroll
    for (int j = 1; j < 8; ++j) mx = fmaxf(mx, v[j]);
#pragma unroll
    for (int msk = 1; msk < 16; msk <<= 1) mx = fmaxf(mx, __shfl_xor(mx, msk));
    float e[8]; float ssum = 0.f;
#pragma unroll
    for (int j = 0; j < 8; ++j) { e[j] = __expf(v[j] - mx); ssum += e[j]; }
#pragma unroll
    for (int msk = 1; msk < 16; msk <<= 1) ssum += __shfl_xor(ssum, msk);
    float invs = __frcp_rn(ssum);
    float gv[8];
#pragma unroll
    for (int j = 0; j < 8; ++j) gv[j] = (seg == 2) ? tanh_fast(v[j]) : e[j] * invs;
    int q = lane & 15;
    float fv[8], iv[8], sv[8], ov[8];
#pragma unroll
    for (int j = 0; j < 8; ++j) {
        fv[j] = __shfl(gv[j], q);
        iv[j] = __shfl(gv[j], 16 + q);
        sv[j] = __shfl(gv[j], 32 + q);
        ov[j] = __shfl(gv[j], 48 + q);
    }
    if (lane < 16) {
        size_t cb = (size_t)t*128 + lane*8;
        float4 c0v = *(float4*)(Cst + cb); float4 c1v = *(float4*)(Cst + cb + 4);
        float cp[8] = {c0v.x,c0v.y,c0v.z,c0v.w,c1v.x,c1v.y,c1v.z,c1v.w};
        float cn[8], hn[8];
#pragma unroll
        for (int j = 0; j < 8; ++j) {
            cn[j] = fmaf(fv[j], cp[j], iv[j] * sv[j]);
            hn[j] = ov[j] * tanh_fast(cn[j]);
        }
        *(float4*)(Cst + cb)     = make_float4(cn[0],cn[1],cn[2],cn[3]);
        *(float4*)(Cst + cb + 4) = make_float4(cn[4],cn[5],cn[6],cn[7]);
        *(float4*)(hs_s + cb)    = make_float4(hn[0],hn[1],hn[2],hn[3]);
        *(float4*)(hs_s + cb + 4)= make_float4(hn[4],hn[5],hn[6],hn[7]);
        u32 p0 = (u32)f2bf(hn[0]) | ((u32)f2bf(hn[1])<<16);
        u32 p1 = (u32)f2bf(hn[2]) | ((u32)f2bf(hn[3])<<16);
        u32 p2 = (u32)f2bf(hn[4]) | ((u32)f2bf(hn[5])<<16);
        u32 p3 = (u32)f2bf(hn[6]) | ((u32)f2bf(hn[7])<<16);
        *(uint4*)(Hstb + cb) = make_uint4(p0, p1, p2, p3);
    }
}

// ---------------- output gather: [t][c] token-order -> [c][y][x] -----------
__global__ void out_gather_k(const float* __restrict__ src, float* __restrict__ dst)
{
    __shared__ float tile[32][65];
    int y = blockIdx.x, cc = blockIdx.y, s = blockIdx.z;
    const float* sp = src + (size_t)s*524288;
    float* dp = dst + (size_t)s*524288;
    int tid = threadIdx.x;
    {
        int xi = tid >> 2, cq = tid & 3;
        int t = ((y>>2)*16 + (xi>>2))*16 + (y&3)*4 + (xi&3);
        const float* p = sp + (size_t)t*128 + cc*32 + cq*8;
        float4 a = ((const float4*)p)[0], b2 = ((const float4*)p)[1];
        tile[cq*8+0][xi]=a.x; tile[cq*8+1][xi]=a.y; tile[cq*8+2][xi]=a.z; tile[cq*8+3][xi]=a.w;
        tile[cq*8+4][xi]=b2.x; tile[cq*8+5][xi]=b2.y; tile[cq*8+6][xi]=b2.z; tile[cq*8+7][xi]=b2.w;
    }
    __syncthreads();
    {
        int ci = tid >> 3, xq = tid & 7;
        float* p = dp + (size_t)(cc*32 + ci)*4096 + y*64 + xq*8;
#pragma unroll
        for (int e = 0; e < 8; ++e) p[e] = tile[ci][xq*8 + e];
    }
}

// ---------------------------------------------------------------------------
extern "C" void kernel_launch(void* const* d_in, const int* in_sizes, int n_in,
                              void* d_out, int out_size, void* d_ws, size_t ws_size,
                              hipStream_t stream)
{
    const float* x      = (const float*)d_in[0];
    const float* h0     = (const float*)d_in[1];
    const float* c0     = (const float*)d_in[2];
    const float* conv_w = (const float*)d_in[3];
    const float* conv_b = (const float*)d_in[4];
    const float* qkv1_w = (const float*)d_in[5];
    const float* qkv1_b = (const float*)d_in[6];
    const float* m1w1   = (const float*)d_in[7];
    const float* m1b1   = (const float*)d_in[8];
    const float* m1w2   = (const float*)d_in[9];
    const float* m1b2   = (const float*)d_in[10];
    const float* qkv2_w = (const float*)d_in[11];
    const float* qkv2_b = (const float*)d_in[12];
    const float* m2w1   = (const float*)d_in[13];
    const float* m2b1   = (const float*)d_in[14];
    const float* m2w2   = (const float*)d_in[15];
    const float* m2b2   = (const float*)d_in[16];
    const float* wx     = (const float*)d_in[17];
    const float* wh     = (const float*)d_in[18];
    const float* bh     = (const float*)d_in[19];
    float* out = (float*)d_out;

    char* ws = (char*)d_ws;
    u16*   XAb   = (u16*)(ws);                       // [65536][512] bf16 (REG0)
    u16*   Hb    = (u16*)(ws);                       // [65536][512] bf16 (reuse)
    u16*   GXb   = (u16*)(ws);                       // [65536][512] bf16 (reuse)
    u16*   QKVb  = (u16*)(ws + 67108864);            // [65536][384] bf16
    float* A1f   = (float*)(ws + 117440512);         // [65536][128] f32
    u16*   A1b   = (u16*)(ws + 150994944);           // [65536][128] bf16
    float* HSW   = (float*)(ws + 167772160);         // [16][4096][128] f32
    float* Cst   = (float*)(ws + 201326592);         // [4096][128] f32
    u16*   Hstb  = (u16*)(ws + 203423744);           // [4096][128] bf16
    float* gates = (float*)(ws + 204472320);         // [4096][512] f32
    u16*   Wb    = (u16*)(ws + 212860928);           // 557056 bf16 weights

    const u16* Wconv = Wb;
    const u16* Wq1   = Wb + 65536;
    const u16* Wm1a  = Wb + 114688;
    const u16* Wm1b  = Wb + 180224;
    const u16* Wq2   = Wb + 245760;
    const u16* Wm2a  = Wb + 294912;
    const u16* Wm2b  = Wb + 360448;
    const u16* Wwx   = Wb + 425984;
    const u16* Wwh   = Wb + 491520;

    conv_weights_k<<<2177, 256, 0, stream>>>(conv_w, qkv1_w, m1w1, m1w2, qkv2_w,
                                             m2w1, m2w2, wx, wh, Wb);
    xa_build_k<<<dim3(64, 4, 16), 256, 0, stream>>>(x, XAb);
    lstm_init_k<<<128, 256, 0, stream>>>(h0, c0, Hstb, Cst);

    // conv as GEMM -> A1f + A1b
    gemm_bf16_k<<<dim3(512, 1), 256, 0, stream>>>(XAb, Wconv, conv_b, A1f, A1b,
                                                  nullptr, 128, 512, 12);
    // block 1
    gemm_bf16_k<<<dim3(512, 3), 256, 0, stream>>>(A1b, Wq1, qkv1_b, nullptr, QKVb,
                                                  nullptr, 384, 128, 8);
    attn1_k<<<512, 256, 0, stream>>>(QKVb, A1f, A1b);
    gemm_bf16_k<<<dim3(512, 4), 256, 0, stream>>>(A1b, Wm1a, m1b1, nullptr, Hb,
                                                  nullptr, 512, 128, 9);
    gemm_bf16_k<<<dim3(512, 1), 256, 0, stream>>>(Hb, Wm1b, m1b2, A1f, A1b,
                                                  A1f, 128, 512, 14);
    // block 2
    gemm_bf16_k<<<dim3(512, 3), 256, 0, stream>>>(A1b, Wq2, qkv2_b, nullptr, QKVb,
                                                  nullptr, 384, 128, 8);
    attn2_k<<<512, 256, 0, stream>>>(QKVb, A1f, A1b);
    gemm_bf16_k<<<dim3(512, 4), 256, 0, stream>>>(A1b, Wm2a, m2b1, nullptr, Hb,
                                                  nullptr, 512, 128, 9);
    gemm_bf16_k<<<dim3(512, 1), 256, 0, stream>>>(Hb, Wm2b, m2b2, A1f, A1b,
                                                  A1f, 128, 512, 14);
    // GX = Wx@A1 + bh (bf16, token order)
    gemm_bf16_k<<<dim3(512, 4), 256, 0, stream>>>(A1b, Wwx, bh, nullptr, GXb,
                                                  nullptr, 512, 128, 8);
    // LSTM recurrence
    for (int s = 0; s < 16; ++s) {
        gemm_bf16_k<<<dim3(32, 4), 256, 0, stream>>>(Hstb, Wwh, nullptr, gates, nullptr,
                                                     (const void*)(GXb + (size_t)s*2097152),
                                                     512, 128, 20);
        lstm_gate_k<<<1024, 256, 0, stream>>>(gates, Cst, Hstb, HSW + (size_t)s*524288);
    }

    // outputs: hs, hf (= hs[15]), Cf
    out_gather_k<<<dim3(64, 4, 16), 256, 0, stream>>>(HSW, out);
    out_gather_k<<<dim3(64, 4, 1), 256, 0, stream>>>(HSW + 15*524288, out + 8388608);
    out_gather_k<<<dim3(64, 4, 1), 256, 0, stream>>>(Cst, out + 8912896);
}

// Round 3
// 1115.093 us; speedup vs baseline: 1.7425x; 1.3035x over previous
//
#include <hip/hip_runtime.h>
#include <math.h>

typedef unsigned short u16;
typedef unsigned int   u32;
typedef __attribute__((ext_vector_type(8))) short s16x8;   // 8 bf16 (4 VGPR)
typedef __attribute__((ext_vector_type(4))) float f32x4;

// ---------------- helpers ---------------------------------------------------
__device__ __forceinline__ u16 f2bf(float f) {
    union { float f; u32 u; } a; a.f = f;
    return (u16)((a.u + 0x7fffu + ((a.u >> 16) & 1u)) >> 16);
}
__device__ __forceinline__ float bf2f(u16 h) {
    union { u32 u; float f; } a; a.u = ((u32)h) << 16; return a.f;
}
__device__ __forceinline__ float bflo(u32 u){ union{u32 i;float f;} a; a.i = u<<16; return a.f; }
__device__ __forceinline__ float bfhi(u32 u){ union{u32 i;float f;} a; a.i = u & 0xffff0000u; return a.f; }

__device__ __forceinline__ float tanh_fast(float x) {
    float xc = fminf(fmaxf(x, -15.f), 15.f);
    float e = __expf(2.f * xc);
    return (e - 1.f) * __frcp_rn(e + 1.f);
}
__device__ __forceinline__ float erf_fast(float x) {
    float ax = fabsf(x);
    float t = __frcp_rn(fmaf(0.3275911f, ax, 1.f));
    float poly = t*(0.254829592f + t*(-0.284496736f + t*(1.421413741f +
                 t*(-1.453152027f + t*1.061405429f))));
    float y = 1.f - poly * __expf(-ax*ax);
    return copysignf(y, x);
}
__device__ __forceinline__ float gelu_fast(float v) {
    return v * 0.5f * (1.f + erf_fast(v * 0.70710678118654752440f));
}

__device__ __forceinline__ void gload16(const void* g, void* l) {
    __builtin_amdgcn_global_load_lds(
        (const __attribute__((address_space(1))) void*)g,
        (__attribute__((address_space(3))) void*)l, 16, 0, 0);
}

// ---------------- bf16 MFMA GEMM: C[t][n] = sum_k A[t][k]*B[n][k] ----------
// 128x128 tile, BK=64, 4 waves. flags: 1 gelu, 2 res f32, 4 write Cf,
// 8 write Cb (bf16), 16 res bf16.
__global__ __launch_bounds__(256) void gemm_bf16_k(
    const u16* __restrict__ A, const u16* __restrict__ B,
    const float* __restrict__ bias, float* __restrict__ Cf,
    u16* __restrict__ Cb, const void* __restrict__ Res,
    int N, int K, int flags)
{
    __shared__ u16 As[128 * 64];
    __shared__ u16 Bs[128 * 64];
    const int tid = threadIdx.x;
    const int w = tid >> 6, lane = tid & 63;
    const int wr = w >> 1, wc = w & 1;
    const int t0 = blockIdx.x * 128, n0 = blockIdx.y * 128;
    const int ns = K >> 6;
    const int rsub = lane >> 3, ssub = lane & 7;

    f32x4 acc[4][4];
#pragma unroll
    for (int m = 0; m < 4; ++m)
#pragma unroll
        for (int n = 0; n < 4; ++n) acc[m][n] = (f32x4){0.f,0.f,0.f,0.f};

    const u16* Abase = A + (size_t)t0 * K;
    const u16* Bbase = B + (size_t)n0 * K;

    for (int s = 0; s < ns; ++s) {
#pragma unroll
        for (int r = 0; r < 4; ++r) {
            int row = r*32 + w*8 + rsub;
            int c16 = ssub ^ (row & 7);
            gload16(Abase + (size_t)row * K + s*64 + c16*8, As + (r*32 + w*8)*64);
        }
#pragma unroll
        for (int r = 0; r < 4; ++r) {
            int row = r*32 + w*8 + rsub;
            int c16 = ssub ^ (row & 7);
            gload16(Bbase + (size_t)row * K + s*64 + c16*8, Bs + (r*32 + w*8)*64);
        }
        __syncthreads();

#pragma unroll
        for (int kk = 0; kk < 2; ++kk) {
            s16x8 av[4], bv[4];
#pragma unroll
            for (int m = 0; m < 4; ++m) {
                int ra = wr*64 + m*16 + (lane & 15);
                int ca = (kk*4 + (lane >> 4)) ^ (ra & 7);
                av[m] = *(const s16x8*)&As[ra*64 + ca*8];
                int rb = wc*64 + m*16 + (lane & 15);
                int cb2 = (kk*4 + (lane >> 4)) ^ (rb & 7);
                bv[m] = *(const s16x8*)&Bs[rb*64 + cb2*8];
            }
#pragma unroll
            for (int m = 0; m < 4; ++m)
#pragma unroll
                for (int n = 0; n < 4; ++n)
                    acc[m][n] = __builtin_amdgcn_mfma_f32_16x16x32_bf16(
                        av[m], bv[n], acc[m][n], 0, 0, 0);
        }
        __syncthreads();
    }

#pragma unroll
    for (int n = 0; n < 4; ++n) {
        int col = n0 + wc*64 + n*16 + (lane & 15);
        float bv = bias ? bias[col] : 0.f;
#pragma unroll
        for (int m = 0; m < 4; ++m) {
            int row0 = t0 + wr*64 + m*16 + (lane >> 4)*4;
#pragma unroll
            for (int j = 0; j < 4; ++j) {
                size_t off = (size_t)(row0 + j) * N + col;
                float v = acc[m][n][j] + bv;
                if (flags & 1)  v = gelu_fast(v);
                if (flags & 2)  v += ((const float*)Res)[off];
                if (flags & 16) v += bf2f(((const u16*)Res)[off]);
                if (flags & 4)  Cf[off] = v;
                if (flags & 8)  Cb[off] = f2bf(v);
            }
        }
    }
}

// ---------------- XA builder: x NCHW -> token-order [65536][512] bf16 ------
__global__ __launch_bounds__(256) void xa_build_k(const float* __restrict__ x,
                                                  u16* __restrict__ XA)
{
    __shared__ float tile[32][2][129];
    const int y = blockIdx.x, cc = blockIdx.y, b = blockIdx.z;
    const int tid = threadIdx.x;
    {
        int c_i = tid >> 3, rem = tid & 7;
        int yy = rem >> 2, qx = rem & 3;
        const float* p = x + (((size_t)(b*128 + cc*32 + c_i) * 128) + (2*y + yy)) * 128 + qx*32;
#pragma unroll
        for (int e = 0; e < 8; ++e) {
            float4 v = ((const float4*)p)[e];
            tile[c_i][yy][qx*32 + e*4 + 0] = v.x;
            tile[c_i][yy][qx*32 + e*4 + 1] = v.y;
            tile[c_i][yy][qx*32 + e*4 + 2] = v.z;
            tile[c_i][yy][qx*32 + e*4 + 3] = v.w;
        }
    }
    __syncthreads();
    {
        int xo = tid >> 2, kq = tid & 3;
        int ky = kq >> 1, kx = kq & 1;
        size_t t = (size_t)b*4096 + ((y>>2)*16 + (xo>>2))*16 + (y&3)*4 + (xo&3);
        u16* dst = XA + t*512 + kq*128 + cc*32;
        u32 pk[16];
#pragma unroll
        for (int e = 0; e < 16; ++e) {
            float v0 = tile[2*e  ][ky][2*xo + kx];
            float v1 = tile[2*e+1][ky][2*xo + kx];
            pk[e] = (u32)f2bf(v0) | ((u32)f2bf(v1) << 16);
        }
#pragma unroll
        for (int e = 0; e < 4; ++e)
            ((uint4*)dst)[e] = make_uint4(pk[4*e], pk[4*e+1], pk[4*e+2], pk[4*e+3]);
    }
}

// ---------------- weight convert ------------------------------------------
__global__ void conv_weights_k(const float* __restrict__ conv_w, const float* __restrict__ qkv1_w,
    const float* __restrict__ m1w1, const float* __restrict__ m1w2,
    const float* __restrict__ qkv2_w, const float* __restrict__ m2w1,
    const float* __restrict__ m2w2, const float* __restrict__ wx,
    const float* __restrict__ wh, u16* __restrict__ Wb)
{
    int idx = blockIdx.x * 256 + threadIdx.x;
    if (idx >= 557056) return;
    float v;
    if (idx < 65536) { int o = idx >> 9, k = idx & 511; v = conv_w[((o*128 + (k & 127)) << 2) + (k >> 7)]; }
    else if (idx < 114688) v = qkv1_w[idx - 65536];
    else if (idx < 180224) v = m1w1[idx - 114688];
    else if (idx < 245760) v = m1w2[idx - 180224];
    else if (idx < 294912) v = qkv2_w[idx - 245760];
    else if (idx < 360448) v = m2w1[idx - 294912];
    else if (idx < 425984) v = m2w2[idx - 360448];
    else if (idx < 491520) v = wx[idx - 425984];
    else v = wh[idx - 491520];
    Wb[idx] = f2bf(v);
}

// ---------------- MSA1: 1 wave per window; lane = (r, h, half) -------------
__global__ __launch_bounds__(256) void attn1_k(const u16* __restrict__ QKV,
                                               float* __restrict__ A1f,
                                               u16* __restrict__ A1b)
{
    int bx = blockIdx.x;                 // 1024
    int b = bx >> 6, g4 = bx & 63;
    int w = threadIdx.x >> 6, lane = threadIdx.x & 63;
    int g = g4*4 + w;
    int r = lane & 15, h = (lane >> 4) & 1, half = lane >> 5;
    size_t tb = ((size_t)(b*256 + g)) * 16;
    float qr[32];
    {
        const uint4* qp = (const uint4*)(QKV + (tb + r)*384 + h*64 + half*32);
#pragma unroll
        for (int i = 0; i < 4; ++i) {
            uint4 u = qp[i];
            qr[8*i+0]=bflo(u.x); qr[8*i+1]=bfhi(u.x); qr[8*i+2]=bflo(u.y); qr[8*i+3]=bfhi(u.y);
            qr[8*i+4]=bflo(u.z); qr[8*i+5]=bfhi(u.z); qr[8*i+6]=bflo(u.w); qr[8*i+7]=bfhi(u.w);
        }
    }
    float sc[16]; float mx = -1e30f;
#pragma unroll
    for (int k = 0; k < 16; ++k) {
        const uint4* kp = (const uint4*)(QKV + (tb + k)*384 + 128 + h*64 + half*32);
        float s0 = 0.f, s1 = 0.f, s2 = 0.f, s3 = 0.f;
#pragma unroll
        for (int i = 0; i < 4; ++i) {
            uint4 u = kp[i];
            float* sp = (i == 0) ? &s0 : (i == 1) ? &s1 : (i == 2) ? &s2 : &s3;
            float s = *sp;
            s = fmaf(qr[8*i+0], bflo(u.x), s); s = fmaf(qr[8*i+1], bfhi(u.x), s);
            s = fmaf(qr[8*i+2], bflo(u.y), s); s = fmaf(qr[8*i+3], bfhi(u.y), s);
            s = fmaf(qr[8*i+4], bflo(u.z), s); s = fmaf(qr[8*i+5], bfhi(u.z), s);
            s = fmaf(qr[8*i+6], bflo(u.w), s); s = fmaf(qr[8*i+7], bfhi(u.w), s);
            *sp = s;
        }
        float s = (s0 + s1) + (s2 + s3);
        s += __shfl_xor(s, 32);
        sc[k] = s * 0.08838834764831845f;
        mx = fmaxf(mx, sc[k]);
    }
    float sum = 0.f;
#pragma unroll
    for (int k = 0; k < 16; ++k) { sc[k] = __expf(sc[k] - mx); sum += sc[k]; }
    float inv = __frcp_rn(sum);
    float outv[32] = {};
#pragma unroll
    for (int k = 0; k < 16; ++k) {
        float p = sc[k] * inv;
        const uint4* vp = (const uint4*)(QKV + (tb + k)*384 + 256 + h*64 + half*32);
#pragma unroll
        for (int i = 0; i < 4; ++i) {
            uint4 u = vp[i];
            outv[8*i+0] = fmaf(p, bflo(u.x), outv[8*i+0]); outv[8*i+1] = fmaf(p, bfhi(u.x), outv[8*i+1]);
            outv[8*i+2] = fmaf(p, bflo(u.y), outv[8*i+2]); outv[8*i+3] = fmaf(p, bfhi(u.y), outv[8*i+3]);
            outv[8*i+4] = fmaf(p, bflo(u.z), outv[8*i+4]); outv[8*i+5] = fmaf(p, bfhi(u.z), outv[8*i+5]);
            outv[8*i+6] = fmaf(p, bflo(u.w), outv[8*i+6]); outv[8*i+7] = fmaf(p, bfhi(u.w), outv[8*i+7]);
        }
    }
    float* dst = A1f + (tb + r)*128 + h*64 + half*32;
    u16*  dstb = A1b + (tb + r)*128 + h*64 + half*32;
#pragma unroll
    for (int i = 0; i < 8; ++i) {
        float4 o = ((float4*)dst)[i];
        o.x += outv[4*i]; o.y += outv[4*i+1]; o.z += outv[4*i+2]; o.w += outv[4*i+3];
        ((float4*)dst)[i] = o;
        u32 p0 = (u32)f2bf(o.x) | ((u32)f2bf(o.y) << 16);
        u32 p1 = (u32)f2bf(o.z) | ((u32)f2bf(o.w) << 16);
        ((uint2*)dstb)[i] = make_uint2(p0, p1);
    }
}

// ---------------- MSA2: q-split x2, lane-pair dim split, tile rescale ------
__global__ __launch_bounds__(256) void attn2_k(const u16* __restrict__ QKV,
                                               float* __restrict__ A1f,
                                               u16* __restrict__ A1b)
{
    __shared__ float Ks[64][68];
    __shared__ float Vs[64][68];
    int bx = blockIdx.x;                 // 1024 = b(16) x l(16) x h(2) x qh(2)
    int b = bx >> 6, l = (bx >> 2) & 15, h = (bx >> 1) & 1, qh = bx & 1;
    int tid = threadIdx.x;
    int wv = tid >> 6, lane = tid & 63;
    int q = qh*128 + wv*32 + (lane & 31);
    int half = lane >> 5;
    size_t tq = ((size_t)(b*256 + q))*16 + l;
    float qr[32];
    {
        const uint4* qp = (const uint4*)(QKV + tq*384 + h*64 + half*32);
#pragma unroll
        for (int i = 0; i < 4; ++i) {
            uint4 u = qp[i];
            qr[8*i+0]=bflo(u.x); qr[8*i+1]=bfhi(u.x); qr[8*i+2]=bflo(u.y); qr[8*i+3]=bfhi(u.y);
            qr[8*i+4]=bflo(u.z); qr[8*i+5]=bfhi(u.z); qr[8*i+6]=bflo(u.w); qr[8*i+7]=bfhi(u.w);
        }
    }
    float outv[32] = {};
    float m = -1e30f, sum = 0.f;
    for (int ch = 0; ch < 4; ++ch) {
        __syncthreads();
        {   // stage 64 K rows + 64 V rows (bf16 -> f32), full 64 dims
            int row = tid & 63, part = tid >> 6;       // part: 16 cols
            size_t tk = ((size_t)(b*256 + ch*64 + row))*16 + l;
            const uint4* kp = (const uint4*)(QKV + tk*384 + 128 + h*64 + part*16);
            const uint4* vp = (const uint4*)(QKV + tk*384 + 256 + h*64 + part*16);
#pragma unroll
            for (int q2 = 0; q2 < 2; ++q2) {
                uint4 u = kp[q2];
                float4* kd = (float4*)&Ks[row][part*16 + q2*8];
                kd[0] = make_float4(bflo(u.x), bfhi(u.x), bflo(u.y), bfhi(u.y));
                kd[1] = make_float4(bflo(u.z), bfhi(u.z), bflo(u.w), bfhi(u.w));
                uint4 v = vp[q2];
                float4* vd = (float4*)&Vs[row][part*16 + q2*8];
                vd[0] = make_float4(bflo(v.x), bfhi(v.x), bflo(v.y), bfhi(v.y));
                vd[1] = make_float4(bflo(v.z), bfhi(v.z), bflo(v.w), bfhi(v.w));
            }
        }
        __syncthreads();
        for (int sub = 0; sub < 4; ++sub) {
            float sc[16]; float smax = -1e30f;
#pragma unroll
            for (int k2 = 0; k2 < 16; ++k2) {
                const float4* kr = (const float4*)&Ks[sub*16 + k2][half*32];
                float s0=0.f, s1=0.f, s2=0.f, s3=0.f;
                {
                    float4 a0=kr[0], a1=kr[1], a2=kr[2], a3=kr[3];
                    s0 = fmaf(qr[0], a0.x, s0); s0 = fmaf(qr[1], a0.y, s0);
                    s0 = fmaf(qr[2], a0.z, s0); s0 = fmaf(qr[3], a0.w, s0);
                    s1 = fmaf(qr[4], a1.x, s1); s1 = fmaf(qr[5], a1.y, s1);
                    s1 = fmaf(qr[6], a1.z, s1); s1 = fmaf(qr[7], a1.w, s1);
                    s2 = fmaf(qr[8], a2.x, s2); s2 = fmaf(qr[9], a2.y, s2);
                    s2 = fmaf(qr[10], a2.z, s2); s2 = fmaf(qr[11], a2.w, s2);
                    s3 = fmaf(qr[12], a3.x, s3); s3 = fmaf(qr[13], a3.y, s3);
                    s3 = fmaf(qr[14], a3.z, s3); s3 = fmaf(qr[15], a3.w, s3);
                }
                {
                    float4 a0=kr[4], a1=kr[5], a2=kr[6], a3=kr[7];
                    s0 = fmaf(qr[16], a0.x, s0); s0 = fmaf(qr[17], a0.y, s0);
                    s0 = fmaf(qr[18], a0.z, s0); s0 = fmaf(qr[19], a0.w, s0);
                    s1 = fmaf(qr[20], a1.x, s1); s1 = fmaf(qr[21], a1.y, s1);
                    s1 = fmaf(qr[22], a1.z, s1); s1 = fmaf(qr[23], a1.w, s1);
                    s2 = fmaf(qr[24], a2.x, s2); s2 = fmaf(qr[25], a2.y, s2);
                    s2 = fmaf(qr[26], a2.z, s2); s2 = fmaf(qr[27], a2.w, s2);
                    s3 = fmaf(qr[28], a3.x, s3); s3 = fmaf(qr[29], a3.y, s3);
                    s3 = fmaf(qr[30], a3.z, s3); s3 = fmaf(qr[31], a3.w, s3);
                }
                float s = (s0 + s1) + (s2 + s3);
                s += __shfl_xor(s, 32);
                sc[k2] = s * 0.08838834764831845f;
                smax = fmaxf(smax, sc[k2]);
            }
            float nm = fmaxf(m, smax);
            float corr = __expf(m - nm);
            sum *= corr;
#pragma unroll
            for (int d = 0; d < 32; ++d) outv[d] *= corr;
            m = nm;
#pragma unroll
            for (int k2 = 0; k2 < 16; ++k2) {
                float p = __expf(sc[k2] - m);
                sum += p;
                const float4* vr = (const float4*)&Vs[sub*16 + k2][half*32];
#pragma unroll
                for (int d = 0; d < 8; ++d) {
                    float4 vv = vr[d];
                    outv[4*d]   = fmaf(p, vv.x, outv[4*d]);
                    outv[4*d+1] = fmaf(p, vv.y, outv[4*d+1]);
                    outv[4*d+2] = fmaf(p, vv.z, outv[4*d+2]);
                    outv[4*d+3] = fmaf(p, vv.w, outv[4*d+3]);
                }
            }
        }
    }
    float inv = __frcp_rn(sum);
    float* dst = A1f + tq*128 + h*64 + half*32;
    u16*  dstb = A1b + tq*128 + h*64 + half*32;
#pragma unroll
    for (int i = 0; i < 8; ++i) {
        float4 o = ((float4*)dst)[i];
        o.x += outv[4*i] * inv;   o.y += outv[4*i+1] * inv;
        o.z += outv[4*i+2] * inv; o.w += outv[4*i+3] * inv;
        ((float4*)dst)[i] = o;
        u32 p0 = (u32)f2bf(o.x) | ((u32)f2bf(o.y) << 16);
        u32 p1 = (u32)f2bf(o.z) | ((u32)f2bf(o.w) << 16);
        ((uint2*)dstb)[i] = make_uint2(p0, p1);
    }
}

// ---------------- LSTM init: h0/c0 NCHW -> token-order states --------------
__global__ void lstm_init_k(const float* __restrict__ h0, const float* __restrict__ c0,
                            u16* __restrict__ H0b, float* __restrict__ Cst)
{
    int idx = blockIdx.x * 256 + threadIdx.x;     // 32768
    int t = idx >> 3, q = idx & 7;
    int g = t >> 4, l = t & 15;
    int y = (g >> 4)*4 + (l >> 2);
    int x = (g & 15)*4 + (l & 3);
    int hw = y*64 + x;
    u32 pk[8]; float cs[16];
#pragma unroll
    for (int e = 0; e < 16; ++e) {
        int c = q*16 + e;
        float hv = h0[(size_t)c*4096 + hw];
        cs[e] = c0[(size_t)c*4096 + hw];
        if (e & 1) pk[e>>1] |= ((u32)f2bf(hv)) << 16;
        else       pk[e>>1]  = (u32)f2bf(hv);
    }
    u16* hd = H0b + (size_t)t*128 + q*16;
    ((uint4*)hd)[0] = make_uint4(pk[0], pk[1], pk[2], pk[3]);
    ((uint4*)hd)[1] = make_uint4(pk[4], pk[5], pk[6], pk[7]);
    float* cd = Cst + (size_t)t*128 + q*16;
#pragma unroll
    for (int e = 0; e < 4; ++e)
        ((float4*)cd)[e] = make_float4(cs[4*e], cs[4*e+1], cs[4*e+2], cs[4*e+3]);
}

// ---------------- fused ConvLSTM: all 16 steps in one kernel ---------------
// Token-local recurrence. 256 WGs x 4 waves; WG owns 16 tokens.
// Wave w owns gate segment w (cols 128w..128w+128); its Wh panel in VGPRs.
// h: bf16 in XOR-swizzled LDS; c: f32 in regs; GX: double-buffered LDS.
__global__ __launch_bounds__(256, 1) void lstm_fused_k(
    const u16* __restrict__ Whb, const u16* __restrict__ GXb,
    const u16* __restrict__ H0b, float* __restrict__ Cst,
    float* __restrict__ HSW)
{
    __shared__ u16  Hl[16 * 128];          // 4 KB, swizzled ^((row&7)<<4)
    __shared__ float Gl[16 * 512];         // 32 KB, swizzled ^((t&7)<<5)
    __shared__ u16  GXl[2][8192];          // 2 x 16 KB

    const int tid = threadIdx.x;
    const int w = tid >> 6, lane = tid & 63;
    const int t0 = blockIdx.x * 16;
    const int lr = lane & 15, lg = lane >> 4;   // lg in 0..3

    // Wh B-frags in registers: wave w's 128-col segment, 8 n-tiles x 4 k-steps
    s16x8 wf[8][4];
#pragma unroll
    for (int nt = 0; nt < 8; ++nt)
#pragma unroll
        for (int ks = 0; ks < 4; ++ks)
            wf[nt][ks] = *(const s16x8*)(Whb + (size_t)(w*128 + nt*16 + lr)*128
                                         + ks*32 + lg*8);
    // c state: token lr, channels 32w + lg*8 + j
    float cst[8];
    {
        const float4* cp = (const float4*)(Cst + (size_t)(t0 + lr)*128 + 32*w + lg*8);
        float4 c0v = cp[0], c1v = cp[1];
        cst[0]=c0v.x; cst[1]=c0v.y; cst[2]=c0v.z; cst[3]=c0v.w;
        cst[4]=c1v.x; cst[5]=c1v.y; cst[6]=c1v.z; cst[7]=c1v.w;
    }
    // stage h0 into Hl (swizzled)
    {
        int row = tid >> 4, seg = tid & 15;
        uint4 hv = *(const uint4*)(H0b + (size_t)(t0 + row)*128 + seg*8);
        int db = row*256 + ((seg*16) ^ ((row & 7) << 4));
        *(uint4*)((char*)Hl + db) = hv;
    }
    // prefetch GX step 0
    {
        const u16* src = GXb + (size_t)t0 * 512;
#pragma unroll
        for (int r4 = 0; r4 < 4; ++r4)
            gload16(src + w*2048 + r4*512 + lane*8, &GXl[0][w*2048 + r4*512]);
    }
    asm volatile("s_waitcnt vmcnt(0)" ::: "memory");
    __syncthreads();

    for (int s = 0; s < 16; ++s) {
        const int cur = s & 1;
        // prefetch next step's GX
        if (s < 15) {
            const u16* src = GXb + ((size_t)((s + 1)*4096 + t0))*512;
#pragma unroll
            for (int r4 = 0; r4 < 4; ++r4)
                gload16(src + w*2048 + r4*512 + lane*8, &GXl[cur ^ 1][w*2048 + r4*512]);
        }
        // A-frags from Hl
        s16x8 af[4];
#pragma unroll
        for (int ks = 0; ks < 4; ++ks) {
            int bo = lr*256 + ((ks*64 + lg*16) ^ ((lr & 7) << 4));
            af[ks] = *(const s16x8*)((const char*)Hl + bo);
        }
        // acc init from GX (gates = GX + Wh@h)
        f32x4 acc[8];
        {
            const u16* gx = &GXl[cur][0];
#pragma unroll
            for (int nt = 0; nt < 8; ++nt)
#pragma unroll
                for (int j = 0; j < 4; ++j)
                    acc[nt][j] = bf2f(gx[(lg*4 + j)*512 + 128*w + nt*16 + lr]);
        }
#pragma unroll
        for (int ks = 0; ks < 4; ++ks)
#pragma unroll
            for (int nt = 0; nt < 8; ++nt)
                acc[nt] = __builtin_amdgcn_mfma_f32_16x16x32_bf16(
                    af[ks], wf[nt][ks], acc[nt], 0, 0, 0);
        // nonlinearity: waves 0,1,3 channel-softmax; wave 2 tanh
        if (w != 2) {
#pragma unroll
            for (int j = 0; j < 4; ++j) {
                float mx = acc[0][j];
#pragma unroll
                for (int nt = 1; nt < 8; ++nt) mx = fmaxf(mx, acc[nt][j]);
#pragma unroll
                for (int msk = 1; msk < 16; msk <<= 1) mx = fmaxf(mx, __shfl_xor(mx, msk));
                float ssum = 0.f;
#pragma unroll
                for (int nt = 0; nt < 8; ++nt) {
                    float e = __expf(acc[nt][j] - mx);
                    acc[nt][j] = e; ssum += e;
                }
#pragma unroll
                for (int msk = 1; msk < 16; msk <<= 1) ssum += __shfl_xor(ssum, msk);
                float inv = __frcp_rn(ssum);
#pragma unroll
                for (int nt = 0; nt < 8; ++nt) acc[nt][j] *= inv;
            }
        } else {
#pragma unroll
            for (int nt = 0; nt < 8; ++nt)
#pragma unroll
                for (int j = 0; j < 4; ++j)
                    acc[nt][j] = tanh_fast(acc[nt][j]);
        }
        // write gate segment to Gl (swizzled)
#pragma unroll
        for (int nt = 0; nt < 8; ++nt)
#pragma unroll
            for (int j = 0; j < 4; ++j) {
                int t = lg*4 + j;
                int bo = (t*2048 + (w*128 + nt*16 + lr)*4) ^ ((t & 7) << 5);
                *(float*)((char*)Gl + bo) = acc[nt][j];
            }
        __syncthreads();
        // combine: lane handles token lr, channels 32w + lg*8 + j
        float fv[8], iv[8], sv[8], ov[8];
        {
            int colb = (32*w + lg*8)*4;
#pragma unroll
            for (int g = 0; g < 4; ++g) {
                int bo = (lr*2048 + g*512 + colb) ^ ((lr & 7) << 5);
                float4 a = *(const float4*)((const char*)Gl + bo);
                float4 b2 = *(const float4*)((const char*)Gl + (bo + 16));
                float* dstv = (g == 0) ? fv : (g == 1) ? iv : (g == 2) ? sv : ov;
                dstv[0]=a.x; dstv[1]=a.y; dstv[2]=a.z; dstv[3]=a.w;
                dstv[4]=b2.x; dstv[5]=b2.y; dstv[6]=b2.z; dstv[7]=b2.w;
            }
        }
        float hn[8];
#pragma unroll
        for (int j = 0; j < 8; ++j) {
            cst[j] = fmaf(fv[j], cst[j], iv[j] * sv[j]);
            hn[j] = ov[j] * tanh_fast(cst[j]);
        }
        // h -> Hl (bf16, swizzled)
        {
            u32 p0 = (u32)f2bf(hn[0]) | ((u32)f2bf(hn[1])<<16);
            u32 p1 = (u32)f2bf(hn[2]) | ((u32)f2bf(hn[3])<<16);
            u32 p2 = (u32)f2bf(hn[4]) | ((u32)f2bf(hn[5])<<16);
            u32 p3 = (u32)f2bf(hn[6]) | ((u32)f2bf(hn[7])<<16);
            int bo = (lr*256 + (32*w + lg*8)*2) ^ ((lr & 7) << 4);
            *(uint4*)((char*)Hl + bo) = make_uint4(p0, p1, p2, p3);
        }
        // hs -> global (f32, token order)
        {
            float* hp = HSW + ((size_t)s*4096 + t0 + lr)*128 + 32*w + lg*8;
            ((float4*)hp)[0] = make_float4(hn[0], hn[1], hn[2], hn[3]);
            ((float4*)hp)[1] = make_float4(hn[4], hn[5], hn[6], hn[7]);
        }
        __syncthreads();
    }
    // final C
    {
        float* cp = Cst + (size_t)(t0 + lr)*128 + 32*w + lg*8;
        ((float4*)cp)[0] = make_float4(cst[0], cst[1], cst[2], cst[3]);
        ((float4*)cp)[1] = make_float4(cst[4], cst[5], cst[6], cst[7]);
    }
}

// ---------------- output gather: [t][c] token-order -> [c][y][x] -----------
__global__ void out_gather_k(const float* __restrict__ src, float* __restrict__ dst)
{
    __shared__ float tile[32][65];
    int y = blockIdx.x, cc = blockIdx.y, s = blockIdx.z;
    const float* sp = src + (size_t)s*524288;
    float* dp = dst + (size_t)s*524288;
    int tid = threadIdx.x;
    {
        int xi = tid >> 2, cq = tid & 3;
        int t = ((y>>2)*16 + (xi>>2))*16 + (y&3)*4 + (xi&3);
        const float* p = sp + (size_t)t*128 + cc*32 + cq*8;
        float4 a = ((const float4*)p)[0], b2 = ((const float4*)p)[1];
        tile[cq*8+0][xi]=a.x; tile[cq*8+1][xi]=a.y; tile[cq*8+2][xi]=a.z; tile[cq*8+3][xi]=a.w;
        tile[cq*8+4][xi]=b2.x; tile[cq*8+5][xi]=b2.y; tile[cq*8+6][xi]=b2.z; tile[cq*8+7][xi]=b2.w;
    }
    __syncthreads();
    {
        int ci = tid >> 3, xq = tid & 7;
        float* p = dp + (size_t)(cc*32 + ci)*4096 + y*64 + xq*8;
#pragma unroll
        for (int e = 0; e < 8; ++e) p[e] = tile[ci][xq*8 + e];
    }
}

// ---------------------------------------------------------------------------
extern "C" void kernel_launch(void* const* d_in, const int* in_sizes, int n_in,
                              void* d_out, int out_size, void* d_ws, size_t ws_size,
                              hipStream_t stream)
{
    const float* x      = (const float*)d_in[0];
    const float* h0     = (const float*)d_in[1];
    const float* c0     = (const float*)d_in[2];
    const float* conv_w = (const float*)d_in[3];
    const float* conv_b = (const float*)d_in[4];
    const float* qkv1_w = (const float*)d_in[5];
    const float* qkv1_b = (const float*)d_in[6];
    const float* m1w1   = (const float*)d_in[7];
    const float* m1b1   = (const float*)d_in[8];
    const float* m1w2   = (const float*)d_in[9];
    const float* m1b2   = (const float*)d_in[10];
    const float* qkv2_w = (const float*)d_in[11];
    const float* qkv2_b = (const float*)d_in[12];
    const float* m2w1   = (const float*)d_in[13];
    const float* m2b1   = (const float*)d_in[14];
    const float* m2w2   = (const float*)d_in[15];
    const float* m2b2   = (const float*)d_in[16];
    const float* wx     = (const float*)d_in[17];
    const float* wh     = (const float*)d_in[18];
    const float* bh     = (const float*)d_in[19];
    float* out = (float*)d_out;

    char* ws = (char*)d_ws;
    u16*   XAb   = (u16*)(ws);                       // [65536][512] bf16 (reuse)
    u16*   Hb    = (u16*)(ws);                       // [65536][512] bf16 (reuse)
    u16*   GXb   = (u16*)(ws);                       // [65536][512] bf16 (reuse)
    u16*   QKVb  = (u16*)(ws + 67108864);            // [65536][384] bf16
    float* A1f   = (float*)(ws + 117440512);         // [65536][128] f32
    u16*   A1b   = (u16*)(ws + 150994944);           // [65536][128] bf16
    float* HSW   = (float*)(ws + 167772160);         // [16][4096][128] f32
    float* Cst   = (float*)(ws + 201326592);         // [4096][128] f32
    u16*   H0b   = (u16*)(ws + 203423744);           // [4096][128] bf16
    u16*   Wb    = (u16*)(ws + 212860928);           // 557056 bf16 weights

    const u16* Wconv = Wb;
    const u16* Wq1   = Wb + 65536;
    const u16* Wm1a  = Wb + 114688;
    const u16* Wm1b  = Wb + 180224;
    const u16* Wq2   = Wb + 245760;
    const u16* Wm2a  = Wb + 294912;
    const u16* Wm2b  = Wb + 360448;
    const u16* Wwx   = Wb + 425984;
    const u16* Wwh   = Wb + 491520;

    conv_weights_k<<<2177, 256, 0, stream>>>(conv_w, qkv1_w, m1w1, m1w2, qkv2_w,
                                             m2w1, m2w2, wx, wh, Wb);
    xa_build_k<<<dim3(64, 4, 16), 256, 0, stream>>>(x, XAb);
    lstm_init_k<<<128, 256, 0, stream>>>(h0, c0, H0b, Cst);

    // conv as GEMM -> A1f + A1b
    gemm_bf16_k<<<dim3(512, 1), 256, 0, stream>>>(XAb, Wconv, conv_b, A1f, A1b,
                                                  nullptr, 128, 512, 12);
    // block 1
    gemm_bf16_k<<<dim3(512, 3), 256, 0, stream>>>(A1b, Wq1, qkv1_b, nullptr, QKVb,
                                                  nullptr, 384, 128, 8);
    attn1_k<<<1024, 256, 0, stream>>>(QKVb, A1f, A1b);
    gemm_bf16_k<<<dim3(512, 4), 256, 0, stream>>>(A1b, Wm1a, m1b1, nullptr, Hb,
                                                  nullptr, 512, 128, 9);
    gemm_bf16_k<<<dim3(512, 1), 256, 0, stream>>>(Hb, Wm1b, m1b2, A1f, A1b,
                                                  A1f, 128, 512, 14);
    // block 2
    gemm_bf16_k<<<dim3(512, 3), 256, 0, stream>>>(A1b, Wq2, qkv2_b, nullptr, QKVb,
                                                  nullptr, 384, 128, 8);
    attn2_k<<<1024, 256, 0, stream>>>(QKVb, A1f, A1b);
    gemm_bf16_k<<<dim3(512, 4), 256, 0, stream>>>(A1b, Wm2a, m2b1, nullptr, Hb,
                                                  nullptr, 512, 128, 9);
    gemm_bf16_k<<<dim3(512, 1), 256, 0, stream>>>(Hb, Wm2b, m2b2, A1f, A1b,
                                                  A1f, 128, 512, 14);
    // GX = Wx@A1 + bh (bf16, token order)
    gemm_bf16_k<<<dim3(512, 4), 256, 0, stream>>>(A1b, Wwx, bh, nullptr, GXb,
                                                  nullptr, 512, 128, 8);
    // fused LSTM: one kernel, 16 steps internal
    lstm_fused_k<<<256, 256, 0, stream>>>(Wwh, GXb, H0b, Cst, HSW);

    // outputs: hs, hf (= hs[15]), Cf
    out_gather_k<<<dim3(64, 4, 16), 256, 0, stream>>>(HSW, out);
    out_gather_k<<<dim3(64, 4, 1), 256, 0, stream>>>(HSW + 15*524288, out + 8388608);
    out_gather_k<<<dim3(64, 4, 1), 256, 0, stream>>>(Cst, out + 8912896);
}

// Round 4
// 952.691 us; speedup vs baseline: 2.0395x; 1.1705x over previous
//
#include <hip/hip_runtime.h>
#include <math.h>

typedef unsigned short u16;
typedef unsigned int   u32;
typedef __attribute__((ext_vector_type(8))) short s16x8;   // 8 bf16 (4 VGPR)
typedef __attribute__((ext_vector_type(4))) float f32x4;

// ---------------- helpers ---------------------------------------------------
__device__ __forceinline__ u16 f2bf(float f) {
    union { float f; u32 u; } a; a.f = f;
    return (u16)((a.u + 0x7fffu + ((a.u >> 16) & 1u)) >> 16);
}
__device__ __forceinline__ float bf2f(u16 h) {
    union { u32 u; float f; } a; a.u = ((u32)h) << 16; return a.f;
}
__device__ __forceinline__ float bflo(u32 u){ union{u32 i;float f;} a; a.i = u<<16; return a.f; }
__device__ __forceinline__ float bfhi(u32 u){ union{u32 i;float f;} a; a.i = u & 0xffff0000u; return a.f; }

__device__ __forceinline__ u32 cvtpk_bf16(float lo, float hi) {
    u32 r;
    asm("v_cvt_pk_bf16_f32 %0, %1, %2" : "=v"(r) : "v"(lo), "v"(hi));
    return r;
}

__device__ __forceinline__ float tanh_fast(float x) {
    float xc = fminf(fmaxf(x, -15.f), 15.f);
    float e = __expf(2.f * xc);
    return (e - 1.f) * __frcp_rn(e + 1.f);
}
__device__ __forceinline__ float erf_fast(float x) {
    float ax = fabsf(x);
    float t = __frcp_rn(fmaf(0.3275911f, ax, 1.f));
    float poly = t*(0.254829592f + t*(-0.284496736f + t*(1.421413741f +
                 t*(-1.453152027f + t*1.061405429f))));
    float y = 1.f - poly * __expf(-ax*ax);
    return copysignf(y, x);
}
__device__ __forceinline__ float gelu_fast(float v) {
    return v * 0.5f * (1.f + erf_fast(v * 0.70710678118654752440f));
}

__device__ __forceinline__ void gload16(const void* g, void* l) {
    __builtin_amdgcn_global_load_lds(
        (const __attribute__((address_space(1))) void*)g,
        (__attribute__((address_space(3))) void*)l, 16, 0, 0);
}

// ---------------- bf16 MFMA GEMM: C[t][n] = sum_k A[t][k]*B[n][k] ----------
// 128x128 tile, BK=64, 4 waves. flags: 1 gelu, 2 res f32, 4 write Cf,
// 8 write Cb (bf16), 16 res bf16.
__global__ __launch_bounds__(256) void gemm_bf16_k(
    const u16* __restrict__ A, const u16* __restrict__ B,
    const float* __restrict__ bias, float* __restrict__ Cf,
    u16* __restrict__ Cb, const void* __restrict__ Res,
    int N, int K, int flags)
{
    __shared__ u16 As[128 * 64];
    __shared__ u16 Bs[128 * 64];
    const int tid = threadIdx.x;
    const int w = tid >> 6, lane = tid & 63;
    const int wr = w >> 1, wc = w & 1;
    const int t0 = blockIdx.x * 128, n0 = blockIdx.y * 128;
    const int ns = K >> 6;
    const int rsub = lane >> 3, ssub = lane & 7;

    f32x4 acc[4][4];
#pragma unroll
    for (int m = 0; m < 4; ++m)
#pragma unroll
        for (int n = 0; n < 4; ++n) acc[m][n] = (f32x4){0.f,0.f,0.f,0.f};

    const u16* Abase = A + (size_t)t0 * K;
    const u16* Bbase = B + (size_t)n0 * K;

    for (int s = 0; s < ns; ++s) {
#pragma unroll
        for (int r = 0; r < 4; ++r) {
            int row = r*32 + w*8 + rsub;
            int c16 = ssub ^ (row & 7);
            gload16(Abase + (size_t)row * K + s*64 + c16*8, As + (r*32 + w*8)*64);
        }
#pragma unroll
        for (int r = 0; r < 4; ++r) {
            int row = r*32 + w*8 + rsub;
            int c16 = ssub ^ (row & 7);
            gload16(Bbase + (size_t)row * K + s*64 + c16*8, Bs + (r*32 + w*8)*64);
        }
        __syncthreads();

#pragma unroll
        for (int kk = 0; kk < 2; ++kk) {
            s16x8 av[4], bv[4];
#pragma unroll
            for (int m = 0; m < 4; ++m) {
                int ra = wr*64 + m*16 + (lane & 15);
                int ca = (kk*4 + (lane >> 4)) ^ (ra & 7);
                av[m] = *(const s16x8*)&As[ra*64 + ca*8];
                int rb = wc*64 + m*16 + (lane & 15);
                int cb2 = (kk*4 + (lane >> 4)) ^ (rb & 7);
                bv[m] = *(const s16x8*)&Bs[rb*64 + cb2*8];
            }
#pragma unroll
            for (int m = 0; m < 4; ++m)
#pragma unroll
                for (int n = 0; n < 4; ++n)
                    acc[m][n] = __builtin_amdgcn_mfma_f32_16x16x32_bf16(
                        av[m], bv[n], acc[m][n], 0, 0, 0);
        }
        __syncthreads();
    }

#pragma unroll
    for (int n = 0; n < 4; ++n) {
        int col = n0 + wc*64 + n*16 + (lane & 15);
        float bv = bias ? bias[col] : 0.f;
#pragma unroll
        for (int m = 0; m < 4; ++m) {
            int row0 = t0 + wr*64 + m*16 + (lane >> 4)*4;
#pragma unroll
            for (int j = 0; j < 4; ++j) {
                size_t off = (size_t)(row0 + j) * N + col;
                float v = acc[m][n][j] + bv;
                if (flags & 1)  v = gelu_fast(v);
                if (flags & 2)  v += ((const float*)Res)[off];
                if (flags & 16) v += bf2f(((const u16*)Res)[off]);
                if (flags & 4)  Cf[off] = v;
                if (flags & 8)  Cb[off] = f2bf(v);
            }
        }
    }
}

// ---------------- XA builder: x NCHW -> token-order [65536][512] bf16 ------
__global__ __launch_bounds__(256) void xa_build_k(const float* __restrict__ x,
                                                  u16* __restrict__ XA)
{
    __shared__ float tile[32][2][129];
    const int y = blockIdx.x, cc = blockIdx.y, b = blockIdx.z;
    const int tid = threadIdx.x;
    {
        int c_i = tid >> 3, rem = tid & 7;
        int yy = rem >> 2, qx = rem & 3;
        const float* p = x + (((size_t)(b*128 + cc*32 + c_i) * 128) + (2*y + yy)) * 128 + qx*32;
#pragma unroll
        for (int e = 0; e < 8; ++e) {
            float4 v = ((const float4*)p)[e];
            tile[c_i][yy][qx*32 + e*4 + 0] = v.x;
            tile[c_i][yy][qx*32 + e*4 + 1] = v.y;
            tile[c_i][yy][qx*32 + e*4 + 2] = v.z;
            tile[c_i][yy][qx*32 + e*4 + 3] = v.w;
        }
    }
    __syncthreads();
    {
        int xo = tid >> 2, kq = tid & 3;
        int ky = kq >> 1, kx = kq & 1;
        size_t t = (size_t)b*4096 + ((y>>2)*16 + (xo>>2))*16 + (y&3)*4 + (xo&3);
        u16* dst = XA + t*512 + kq*128 + cc*32;
        u32 pk[16];
#pragma unroll
        for (int e = 0; e < 16; ++e) {
            float v0 = tile[2*e  ][ky][2*xo + kx];
            float v1 = tile[2*e+1][ky][2*xo + kx];
            pk[e] = (u32)f2bf(v0) | ((u32)f2bf(v1) << 16);
        }
#pragma unroll
        for (int e = 0; e < 4; ++e)
            ((uint4*)dst)[e] = make_uint4(pk[4*e], pk[4*e+1], pk[4*e+2], pk[4*e+3]);
    }
}

// ---------------- weight convert ------------------------------------------
__global__ void conv_weights_k(const float* __restrict__ conv_w, const float* __restrict__ qkv1_w,
    const float* __restrict__ m1w1, const float* __restrict__ m1w2,
    const float* __restrict__ qkv2_w, const float* __restrict__ m2w1,
    const float* __restrict__ m2w2, const float* __restrict__ wx,
    const float* __restrict__ wh, u16* __restrict__ Wb)
{
    int idx = blockIdx.x * 256 + threadIdx.x;
    if (idx >= 557056) return;
    float v;
    if (idx < 65536) { int o = idx >> 9, k = idx & 511; v = conv_w[((o*128 + (k & 127)) << 2) + (k >> 7)]; }
    else if (idx < 114688) v = qkv1_w[idx - 65536];
    else if (idx < 180224) v = m1w1[idx - 114688];
    else if (idx < 245760) v = m1w2[idx - 180224];
    else if (idx < 294912) v = qkv2_w[idx - 245760];
    else if (idx < 360448) v = m2w1[idx - 294912];
    else if (idx < 425984) v = m2w2[idx - 360448];
    else if (idx < 491520) v = wx[idx - 425984];
    else v = wh[idx - 491520];
    Wb[idx] = f2bf(v);
}

// ---------------- MSA1: 1 wave per window; lane = (r, h, half) -------------
__global__ __launch_bounds__(256) void attn1_k(const u16* __restrict__ QKV,
                                               float* __restrict__ A1f,
                                               u16* __restrict__ A1b)
{
    int bx = blockIdx.x;                 // 1024
    int b = bx >> 6, g4 = bx & 63;
    int w = threadIdx.x >> 6, lane = threadIdx.x & 63;
    int g = g4*4 + w;
    int r = lane & 15, h = (lane >> 4) & 1, half = lane >> 5;
    size_t tb = ((size_t)(b*256 + g)) * 16;
    float qr[32];
    {
        const uint4* qp = (const uint4*)(QKV + (tb + r)*384 + h*64 + half*32);
#pragma unroll
        for (int i = 0; i < 4; ++i) {
            uint4 u = qp[i];
            qr[8*i+0]=bflo(u.x); qr[8*i+1]=bfhi(u.x); qr[8*i+2]=bflo(u.y); qr[8*i+3]=bfhi(u.y);
            qr[8*i+4]=bflo(u.z); qr[8*i+5]=bfhi(u.z); qr[8*i+6]=bflo(u.w); qr[8*i+7]=bfhi(u.w);
        }
    }
    float sc[16]; float mx = -1e30f;
#pragma unroll
    for (int k = 0; k < 16; ++k) {
        const uint4* kp = (const uint4*)(QKV + (tb + k)*384 + 128 + h*64 + half*32);
        float s0 = 0.f, s1 = 0.f, s2 = 0.f, s3 = 0.f;
#pragma unroll
        for (int i = 0; i < 4; ++i) {
            uint4 u = kp[i];
            float* sp = (i == 0) ? &s0 : (i == 1) ? &s1 : (i == 2) ? &s2 : &s3;
            float s = *sp;
            s = fmaf(qr[8*i+0], bflo(u.x), s); s = fmaf(qr[8*i+1], bfhi(u.x), s);
            s = fmaf(qr[8*i+2], bflo(u.y), s); s = fmaf(qr[8*i+3], bfhi(u.y), s);
            s = fmaf(qr[8*i+4], bflo(u.z), s); s = fmaf(qr[8*i+5], bfhi(u.z), s);
            s = fmaf(qr[8*i+6], bflo(u.w), s); s = fmaf(qr[8*i+7], bfhi(u.w), s);
            *sp = s;
        }
        float s = (s0 + s1) + (s2 + s3);
        s += __shfl_xor(s, 32);
        sc[k] = s * 0.08838834764831845f;
        mx = fmaxf(mx, sc[k]);
    }
    float sum = 0.f;
#pragma unroll
    for (int k = 0; k < 16; ++k) { sc[k] = __expf(sc[k] - mx); sum += sc[k]; }
    float inv = __frcp_rn(sum);
    float outv[32] = {};
#pragma unroll
    for (int k = 0; k < 16; ++k) {
        float p = sc[k] * inv;
        const uint4* vp = (const uint4*)(QKV + (tb + k)*384 + 256 + h*64 + half*32);
#pragma unroll
        for (int i = 0; i < 4; ++i) {
            uint4 u = vp[i];
            outv[8*i+0] = fmaf(p, bflo(u.x), outv[8*i+0]); outv[8*i+1] = fmaf(p, bfhi(u.x), outv[8*i+1]);
            outv[8*i+2] = fmaf(p, bflo(u.y), outv[8*i+2]); outv[8*i+3] = fmaf(p, bfhi(u.y), outv[8*i+3]);
            outv[8*i+4] = fmaf(p, bflo(u.z), outv[8*i+4]); outv[8*i+5] = fmaf(p, bfhi(u.z), outv[8*i+5]);
            outv[8*i+6] = fmaf(p, bflo(u.w), outv[8*i+6]); outv[8*i+7] = fmaf(p, bfhi(u.w), outv[8*i+7]);
        }
    }
    float* dst = A1f + (tb + r)*128 + h*64 + half*32;
    u16*  dstb = A1b + (tb + r)*128 + h*64 + half*32;
#pragma unroll
    for (int i = 0; i < 8; ++i) {
        float4 o = ((float4*)dst)[i];
        o.x += outv[4*i]; o.y += outv[4*i+1]; o.z += outv[4*i+2]; o.w += outv[4*i+3];
        ((float4*)dst)[i] = o;
        u32 p0 = (u32)f2bf(o.x) | ((u32)f2bf(o.y) << 16);
        u32 p1 = (u32)f2bf(o.z) | ((u32)f2bf(o.w) << 16);
        ((uint2*)dstb)[i] = make_uint2(p0, p1);
    }
}

// ---------------- V2T builder: QKV V-part -> V2T[b][l][h][d][g] bf16 -------
__global__ __launch_bounds__(256) void v2t_build_k(const u16* __restrict__ QKV,
                                                   u16* __restrict__ V2T)
{
    __shared__ u16 T[256 * 64];          // [g][d], chunk-swizzled e^=(g>>3)&7
    int bx = blockIdx.x;                 // 512 = b(16) x l(16) x h(2)
    int b = bx >> 5, l = (bx >> 1) & 15, h = bx & 1;
    int tid = threadIdx.x;
    {
        int g = tid;
        const uint4* src = (const uint4*)(QKV + (((size_t)(b*256 + g)*16 + l)*384) + 256 + h*64);
#pragma unroll
        for (int e = 0; e < 8; ++e) {
            uint4 u = src[e];
            int ep = e ^ ((g >> 3) & 7);
            *(uint4*)((char*)T + g*128 + ep*16) = u;
        }
    }
    __syncthreads();
    u16* dstb = V2T + ((size_t)(((b*16 + l)*2 + h)*64))*256;
#pragma unroll
    for (int rr = 0; rr < 8; ++rr) {
        int R = rr*256 + tid;            // 0..2047
        int d = R >> 5, ck = R & 31;     // chunk of 8 g
        union { u16 s[8]; uint4 v; } o;
#pragma unroll
        for (int j = 0; j < 8; ++j) {
            int g = ck*8 + j;
            int chunk = (d >> 3) ^ ((g >> 3) & 7);
            o.s[j] = *(const u16*)((const char*)T + g*128 + chunk*16 + (d & 7)*2);
        }
        *(uint4*)(dstb + (size_t)d*256 + ck*8) = o.v;
    }
}

// ---------------- MSA2: MFMA flash attention over 256 windows --------------
// One WG per (b,l,h); 4 waves, wave w owns queries w*64..w*64+63.
// K [256][64] and V^T [64][256] staged bf16 in LDS (XOR-swizzled, one barrier).
// S^T = K*Q (acc: col=q=lane&15, row=key) -> in-lane softmax; P redistributed
// to A-frags via cvt_pk_bf16 + shfl; PV with V^T as B-operand.
__global__ __launch_bounds__(256, 2) void attn2_mfma_k(
    const u16* __restrict__ QKV, const u16* __restrict__ V2T,
    float* __restrict__ A1f, u16* __restrict__ A1b)
{
    __shared__ u16 Ksw[256 * 64];        // 32 KB
    __shared__ u16 Vtw[64 * 256];        // 32 KB
    const int bx = blockIdx.x;           // 512
    const int b = bx >> 5, l = (bx >> 1) & 15, h = bx & 1;
    const int tid = threadIdx.x;
    const int w = tid >> 6, lane = tid & 63;
    const int lq = lane & 15, g = lane >> 4;

    // stage K rows (8 rows per gload16)
    {
        int rsub = lane >> 3, ssub = lane & 7;
#pragma unroll
        for (int r = 0; r < 8; ++r) {
            int row = r*32 + w*8 + rsub;
            size_t t = ((size_t)(b*256 + row))*16 + l;
            gload16(QKV + t*384 + 128 + h*64 + ((ssub ^ (row & 7))*8),
                    Ksw + (r*32 + w*8)*64);
        }
    }
    // stage V^T rows (2 rows per gload16)
    {
        int rsub = lane >> 5, ssub = lane & 31;
        const u16* vb = V2T + ((size_t)(((b*16 + l)*2 + h)*64))*256;
#pragma unroll
        for (int r = 0; r < 8; ++r) {
            int row = r*8 + w*2 + rsub;
            gload16(vb + (size_t)row*256 + ((ssub ^ (row & 7))*8),
                    Vtw + (r*8 + w*2)*256);
        }
    }
    // Q B-frags from global
    s16x8 qf[4][2];
#pragma unroll
    for (int nq = 0; nq < 4; ++nq) {
        int q = w*64 + nq*16 + lq;
        size_t t = ((size_t)(b*256 + q))*16 + l;
#pragma unroll
        for (int kf = 0; kf < 2; ++kf)
            qf[nq][kf] = *(const s16x8*)(QKV + t*384 + h*64 + kf*32 + g*8);
    }
    __syncthreads();

    f32x4 oacc[4][4];                    // [mq][nd]
#pragma unroll
    for (int m = 0; m < 4; ++m)
#pragma unroll
        for (int n = 0; n < 4; ++n) oacc[m][n] = (f32x4){0.f,0.f,0.f,0.f};
    float mrow[4] = {-1e30f,-1e30f,-1e30f,-1e30f};
    float lsum[4] = {0.f,0.f,0.f,0.f};
    const float scale = 0.08838834764831845f;

    for (int kc4 = 0; kc4 < 4; ++kc4) {
        f32x4 skt[4][4];                 // [mk][nq]
#pragma unroll
        for (int m = 0; m < 4; ++m)
#pragma unroll
            for (int n = 0; n < 4; ++n) skt[m][n] = (f32x4){0.f,0.f,0.f,0.f};
#pragma unroll
        for (int mk = 0; mk < 4; ++mk) {
            int row = kc4*64 + mk*16 + lq;
#pragma unroll
            for (int kf = 0; kf < 2; ++kf) {
                s16x8 kfr = *(const s16x8*)&Ksw[row*64 + (((kf*4 + g) ^ (row & 7))*8)];
#pragma unroll
                for (int nq = 0; nq < 4; ++nq)
                    skt[mk][nq] = __builtin_amdgcn_mfma_f32_16x16x32_bf16(
                        kfr, qf[nq][kf], skt[mk][nq], 0, 0, 0);
            }
        }
        // scale + per-q max (q = lane&15; reduce over lane>>4 groups)
        float corr[4];
#pragma unroll
        for (int nq = 0; nq < 4; ++nq) {
            float mx = -1e30f;
#pragma unroll
            for (int mk = 0; mk < 4; ++mk)
#pragma unroll
                for (int j = 0; j < 4; ++j) {
                    skt[mk][nq][j] *= scale;
                    mx = fmaxf(mx, skt[mk][nq][j]);
                }
            mx = fmaxf(mx, __shfl_xor(mx, 16));
            mx = fmaxf(mx, __shfl_xor(mx, 32));
            float nm = fmaxf(mrow[nq], mx);
            corr[nq] = __expf(mrow[nq] - nm);
            mrow[nq] = nm;
        }
        // P = exp(s - m) in place, partial row-sums
#pragma unroll
        for (int nq = 0; nq < 4; ++nq) {
            float ps = 0.f;
#pragma unroll
            for (int mk = 0; mk < 4; ++mk)
#pragma unroll
                for (int j = 0; j < 4; ++j) {
                    float p = __expf(skt[mk][nq][j] - mrow[nq]);
                    skt[mk][nq][j] = p; ps += p;
                }
            ps += __shfl_xor(ps, 16);
            ps += __shfl_xor(ps, 32);
            lsum[nq] = lsum[nq]*corr[nq] + ps;
        }
        // rescale O (stats live at q=lane&15; O rows need q=4g+j)
#pragma unroll
        for (int mq = 0; mq < 4; ++mq)
#pragma unroll
            for (int j = 0; j < 4; ++j) {
                float cO = __shfl(corr[mq], 4*g + j);
#pragma unroll
                for (int nd = 0; nd < 4; ++nd) oacc[mq][nd][j] *= cO;
            }
        // P -> bf16 A-frags (keys 8g..8g+7 per lane) + PV
#pragma unroll
        for (int c = 0; c < 2; ++c) {
            s16x8 paf[4];
#pragma unroll
            for (int mq = 0; mq < 4; ++mq) {
                u32 a0 = cvtpk_bf16(skt[2*c][mq][0],   skt[2*c][mq][1]);
                u32 a1 = cvtpk_bf16(skt[2*c][mq][2],   skt[2*c][mq][3]);
                u32 b0 = cvtpk_bf16(skt[2*c+1][mq][0], skt[2*c+1][mq][1]);
                u32 b1 = cvtpk_bf16(skt[2*c+1][mq][2], skt[2*c+1][mq][3]);
                int s0 = lq + ((g & 1) << 5);
                int s1 = s0 + 16;
                u32 xa0 = __shfl((int)a0, s0), xb0 = __shfl((int)b0, s0);
                u32 xa1 = __shfl((int)a1, s0), xb1 = __shfl((int)b1, s0);
                u32 xa2 = __shfl((int)a0, s1), xb2 = __shfl((int)b0, s1);
                u32 xa3 = __shfl((int)a1, s1), xb3 = __shfl((int)b1, s1);
                union { u32 u[4]; s16x8 v; } pu;
                bool hi = (g >= 2);
                pu.u[0] = hi ? (u32)xb0 : (u32)xa0;
                pu.u[1] = hi ? (u32)xb1 : (u32)xa1;
                pu.u[2] = hi ? (u32)xb2 : (u32)xa2;
                pu.u[3] = hi ? (u32)xb3 : (u32)xa3;
                paf[mq] = pu.v;
            }
            int kc = kc4*2 + c;
#pragma unroll
            for (int nd = 0; nd < 4; ++nd) {
                int d = nd*16 + lq;
                s16x8 vf = *(const s16x8*)((const char*)Vtw +
                            d*512 + (((kc*4 + g) ^ (d & 7))*16));
#pragma unroll
                for (int mq = 0; mq < 4; ++mq)
                    oacc[mq][nd] = __builtin_amdgcn_mfma_f32_16x16x32_bf16(
                        paf[mq], vf, oacc[mq][nd], 0, 0, 0);
            }
        }
    }
    // epilogue: O rows q = w*64 + mq*16 + 4g + j; cols d = nd*16 + lq
    float linv[4];
#pragma unroll
    for (int nq = 0; nq < 4; ++nq) linv[nq] = __frcp_rn(lsum[nq]);
#pragma unroll
    for (int mq = 0; mq < 4; ++mq)
#pragma unroll
        for (int j = 0; j < 4; ++j) {
            float inv = __shfl(linv[mq], 4*g + j);
            size_t t = ((size_t)(b*256 + w*64 + mq*16 + 4*g + j))*16 + l;
#pragma unroll
            for (int nd = 0; nd < 4; ++nd) {
                size_t off = t*128 + h*64 + nd*16 + lq;
                float v = A1f[off] + oacc[mq][nd][j]*inv;
                A1f[off] = v;
                A1b[off] = f2bf(v);
            }
        }
}

// ---------------- LSTM init: h0/c0 NCHW -> token-order states --------------
__global__ void lstm_init_k(const float* __restrict__ h0, const float* __restrict__ c0,
                            u16* __restrict__ H0b, float* __restrict__ Cst)
{
    int idx = blockIdx.x * 256 + threadIdx.x;     // 32768
    int t = idx >> 3, q = idx & 7;
    int g = t >> 4, l = t & 15;
    int y = (g >> 4)*4 + (l >> 2);
    int x = (g & 15)*4 + (l & 3);
    int hw = y*64 + x;
    u32 pk[8]; float cs[16];
#pragma unroll
    for (int e = 0; e < 16; ++e) {
        int c = q*16 + e;
        float hv = h0[(size_t)c*4096 + hw];
        cs[e] = c0[(size_t)c*4096 + hw];
        if (e & 1) pk[e>>1] |= ((u32)f2bf(hv)) << 16;
        else       pk[e>>1]  = (u32)f2bf(hv);
    }
    u16* hd = H0b + (size_t)t*128 + q*16;
    ((uint4*)hd)[0] = make_uint4(pk[0], pk[1], pk[2], pk[3]);
    ((uint4*)hd)[1] = make_uint4(pk[4], pk[5], pk[6], pk[7]);
    float* cd = Cst + (size_t)t*128 + q*16;
#pragma unroll
    for (int e = 0; e < 4; ++e)
        ((float4*)cd)[e] = make_float4(cs[4*e], cs[4*e+1], cs[4*e+2], cs[4*e+3]);
}

// ---------------- fused ConvLSTM: all 16 steps in one kernel ---------------
__global__ __launch_bounds__(256, 1) void lstm_fused_k(
    const u16* __restrict__ Whb, const u16* __restrict__ GXb,
    const u16* __restrict__ H0b, float* __restrict__ Cst,
    float* __restrict__ HSW)
{
    __shared__ u16  Hl[16 * 128];
    __shared__ float Gl[16 * 512];
    __shared__ u16  GXl[2][8192];

    const int tid = threadIdx.x;
    const int w = tid >> 6, lane = tid & 63;
    const int t0 = blockIdx.x * 16;
    const int lr = lane & 15, lg = lane >> 4;

    s16x8 wf[8][4];
#pragma unroll
    for (int nt = 0; nt < 8; ++nt)
#pragma unroll
        for (int ks = 0; ks < 4; ++ks)
            wf[nt][ks] = *(const s16x8*)(Whb + (size_t)(w*128 + nt*16 + lr)*128
                                         + ks*32 + lg*8);
    float cst[8];
    {
        const float4* cp = (const float4*)(Cst + (size_t)(t0 + lr)*128 + 32*w + lg*8);
        float4 c0v = cp[0], c1v = cp[1];
        cst[0]=c0v.x; cst[1]=c0v.y; cst[2]=c0v.z; cst[3]=c0v.w;
        cst[4]=c1v.x; cst[5]=c1v.y; cst[6]=c1v.z; cst[7]=c1v.w;
    }
    {
        int row = tid >> 4, seg = tid & 15;
        uint4 hv = *(const uint4*)(H0b + (size_t)(t0 + row)*128 + seg*8);
        int db = row*256 + ((seg*16) ^ ((row & 7) << 4));
        *(uint4*)((char*)Hl + db) = hv;
    }
    {
        const u16* src = GXb + (size_t)t0 * 512;
#pragma unroll
        for (int r4 = 0; r4 < 4; ++r4)
            gload16(src + w*2048 + r4*512 + lane*8, &GXl[0][w*2048 + r4*512]);
    }
    asm volatile("s_waitcnt vmcnt(0)" ::: "memory");
    __syncthreads();

    for (int s = 0; s < 16; ++s) {
        const int cur = s & 1;
        if (s < 15) {
            const u16* src = GXb + ((size_t)((s + 1)*4096 + t0))*512;
#pragma unroll
            for (int r4 = 0; r4 < 4; ++r4)
                gload16(src + w*2048 + r4*512 + lane*8, &GXl[cur ^ 1][w*2048 + r4*512]);
        }
        s16x8 af[4];
#pragma unroll
        for (int ks = 0; ks < 4; ++ks) {
            int bo = lr*256 + ((ks*64 + lg*16) ^ ((lr & 7) << 4));
            af[ks] = *(const s16x8*)((const char*)Hl + bo);
        }
        f32x4 acc[8];
        {
            const u16* gx = &GXl[cur][0];
#pragma unroll
            for (int nt = 0; nt < 8; ++nt)
#pragma unroll
                for (int j = 0; j < 4; ++j)
                    acc[nt][j] = bf2f(gx[(lg*4 + j)*512 + 128*w + nt*16 + lr]);
        }
#pragma unroll
        for (int ks = 0; ks < 4; ++ks)
#pragma unroll
            for (int nt = 0; nt < 8; ++nt)
                acc[nt] = __builtin_amdgcn_mfma_f32_16x16x32_bf16(
                    af[ks], wf[nt][ks], acc[nt], 0, 0, 0);
        if (w != 2) {
#pragma unroll
            for (int j = 0; j < 4; ++j) {
                float mx = acc[0][j];
#pragma unroll
                for (int nt = 1; nt < 8; ++nt) mx = fmaxf(mx, acc[nt][j]);
#pragma unroll
                for (int msk = 1; msk < 16; msk <<= 1) mx = fmaxf(mx, __shfl_xor(mx, msk));
                float ssum = 0.f;
#pragma unroll
                for (int nt = 0; nt < 8; ++nt) {
                    float e = __expf(acc[nt][j] - mx);
                    acc[nt][j] = e; ssum += e;
                }
#pragma unroll
                for (int msk = 1; msk < 16; msk <<= 1) ssum += __shfl_xor(ssum, msk);
                float inv = __frcp_rn(ssum);
#pragma unroll
                for (int nt = 0; nt < 8; ++nt) acc[nt][j] *= inv;
            }
        } else {
#pragma unroll
            for (int nt = 0; nt < 8; ++nt)
#pragma unroll
                for (int j = 0; j < 4; ++j)
                    acc[nt][j] = tanh_fast(acc[nt][j]);
        }
#pragma unroll
        for (int nt = 0; nt < 8; ++nt)
#pragma unroll
            for (int j = 0; j < 4; ++j) {
                int t = lg*4 + j;
                int bo = (t*2048 + (w*128 + nt*16 + lr)*4) ^ ((t & 7) << 5);
                *(float*)((char*)Gl + bo) = acc[nt][j];
            }
        __syncthreads();
        float fv[8], iv[8], sv[8], ov[8];
        {
            int colb = (32*w + lg*8)*4;
#pragma unroll
            for (int g = 0; g < 4; ++g) {
                int bo = (lr*2048 + g*512 + colb) ^ ((lr & 7) << 5);
                float4 a = *(const float4*)((const char*)Gl + bo);
                float4 b2 = *(const float4*)((const char*)Gl + (bo + 16));
                float* dstv = (g == 0) ? fv : (g == 1) ? iv : (g == 2) ? sv : ov;
                dstv[0]=a.x; dstv[1]=a.y; dstv[2]=a.z; dstv[3]=a.w;
                dstv[4]=b2.x; dstv[5]=b2.y; dstv[6]=b2.z; dstv[7]=b2.w;
            }
        }
        float hn[8];
#pragma unroll
        for (int j = 0; j < 8; ++j) {
            cst[j] = fmaf(fv[j], cst[j], iv[j] * sv[j]);
            hn[j] = ov[j] * tanh_fast(cst[j]);
        }
        {
            u32 p0 = (u32)f2bf(hn[0]) | ((u32)f2bf(hn[1])<<16);
            u32 p1 = (u32)f2bf(hn[2]) | ((u32)f2bf(hn[3])<<16);
            u32 p2 = (u32)f2bf(hn[4]) | ((u32)f2bf(hn[5])<<16);
            u32 p3 = (u32)f2bf(hn[6]) | ((u32)f2bf(hn[7])<<16);
            int bo = (lr*256 + (32*w + lg*8)*2) ^ ((lr & 7) << 4);
            *(uint4*)((char*)Hl + bo) = make_uint4(p0, p1, p2, p3);
        }
        {
            float* hp = HSW + ((size_t)s*4096 + t0 + lr)*128 + 32*w + lg*8;
            ((float4*)hp)[0] = make_float4(hn[0], hn[1], hn[2], hn[3]);
            ((float4*)hp)[1] = make_float4(hn[4], hn[5], hn[6], hn[7]);
        }
        __syncthreads();
    }
    {
        float* cp = Cst + (size_t)(t0 + lr)*128 + 32*w + lg*8;
        ((float4*)cp)[0] = make_float4(cst[0], cst[1], cst[2], cst[3]);
        ((float4*)cp)[1] = make_float4(cst[4], cst[5], cst[6], cst[7]);
    }
}

// ---------------- output gather: [t][c] token-order -> [c][y][x] -----------
__global__ void out_gather_k(const float* __restrict__ src, float* __restrict__ dst)
{
    __shared__ float tile[32][65];
    int y = blockIdx.x, cc = blockIdx.y, s = blockIdx.z;
    const float* sp = src + (size_t)s*524288;
    float* dp = dst + (size_t)s*524288;
    int tid = threadIdx.x;
    {
        int xi = tid >> 2, cq = tid & 3;
        int t = ((y>>2)*16 + (xi>>2))*16 + (y&3)*4 + (xi&3);
        const float* p = sp + (size_t)t*128 + cc*32 + cq*8;
        float4 a = ((const float4*)p)[0], b2 = ((const float4*)p)[1];
        tile[cq*8+0][xi]=a.x; tile[cq*8+1][xi]=a.y; tile[cq*8+2][xi]=a.z; tile[cq*8+3][xi]=a.w;
        tile[cq*8+4][xi]=b2.x; tile[cq*8+5][xi]=b2.y; tile[cq*8+6][xi]=b2.z; tile[cq*8+7][xi]=b2.w;
    }
    __syncthreads();
    {
        int ci = tid >> 3, xq = tid & 7;
        float* p = dp + (size_t)(cc*32 + ci)*4096 + y*64 + xq*8;
#pragma unroll
        for (int e = 0; e < 8; ++e) p[e] = tile[ci][xq*8 + e];
    }
}

// ---------------------------------------------------------------------------
extern "C" void kernel_launch(void* const* d_in, const int* in_sizes, int n_in,
                              void* d_out, int out_size, void* d_ws, size_t ws_size,
                              hipStream_t stream)
{
    const float* x      = (const float*)d_in[0];
    const float* h0     = (const float*)d_in[1];
    const float* c0     = (const float*)d_in[2];
    const float* conv_w = (const float*)d_in[3];
    const float* conv_b = (const float*)d_in[4];
    const float* qkv1_w = (const float*)d_in[5];
    const float* qkv1_b = (const float*)d_in[6];
    const float* m1w1   = (const float*)d_in[7];
    const float* m1b1   = (const float*)d_in[8];
    const float* m1w2   = (const float*)d_in[9];
    const float* m1b2   = (const float*)d_in[10];
    const float* qkv2_w = (const float*)d_in[11];
    const float* qkv2_b = (const float*)d_in[12];
    const float* m2w1   = (const float*)d_in[13];
    const float* m2b1   = (const float*)d_in[14];
    const float* m2w2   = (const float*)d_in[15];
    const float* m2b2   = (const float*)d_in[16];
    const float* wx     = (const float*)d_in[17];
    const float* wh     = (const float*)d_in[18];
    const float* bh     = (const float*)d_in[19];
    float* out = (float*)d_out;

    char* ws = (char*)d_ws;
    u16*   XAb   = (u16*)(ws);                       // [65536][512] bf16 (reuse)
    u16*   Hb    = (u16*)(ws);                       // [65536][512] bf16 (reuse)
    u16*   GXb   = (u16*)(ws);                       // [65536][512] bf16 (reuse)
    u16*   QKVb  = (u16*)(ws + 67108864);            // [65536][384] bf16
    float* A1f   = (float*)(ws + 117440512);         // [65536][128] f32
    u16*   A1b   = (u16*)(ws + 150994944);           // [65536][128] bf16
    float* HSW   = (float*)(ws + 167772160);         // [16][4096][128] f32
    u16*   V2T   = (u16*)(ws + 167772160);           // [16][16][2][64][256] bf16 (dead before LSTM)
    float* Cst   = (float*)(ws + 201326592);         // [4096][128] f32
    u16*   H0b   = (u16*)(ws + 203423744);           // [4096][128] bf16
    u16*   Wb    = (u16*)(ws + 212860928);           // 557056 bf16 weights

    const u16* Wconv = Wb;
    const u16* Wq1   = Wb + 65536;
    const u16* Wm1a  = Wb + 114688;
    const u16* Wm1b  = Wb + 180224;
    const u16* Wq2   = Wb + 245760;
    const u16* Wm2a  = Wb + 294912;
    const u16* Wm2b  = Wb + 360448;
    const u16* Wwx   = Wb + 425984;
    const u16* Wwh   = Wb + 491520;

    conv_weights_k<<<2177, 256, 0, stream>>>(conv_w, qkv1_w, m1w1, m1w2, qkv2_w,
                                             m2w1, m2w2, wx, wh, Wb);
    xa_build_k<<<dim3(64, 4, 16), 256, 0, stream>>>(x, XAb);
    lstm_init_k<<<128, 256, 0, stream>>>(h0, c0, H0b, Cst);

    // conv as GEMM -> A1f + A1b
    gemm_bf16_k<<<dim3(512, 1), 256, 0, stream>>>(XAb, Wconv, conv_b, A1f, A1b,
                                                  nullptr, 128, 512, 12);
    // block 1
    gemm_bf16_k<<<dim3(512, 3), 256, 0, stream>>>(A1b, Wq1, qkv1_b, nullptr, QKVb,
                                                  nullptr, 384, 128, 8);
    attn1_k<<<1024, 256, 0, stream>>>(QKVb, A1f, A1b);
    gemm_bf16_k<<<dim3(512, 4), 256, 0, stream>>>(A1b, Wm1a, m1b1, nullptr, Hb,
                                                  nullptr, 512, 128, 9);
    gemm_bf16_k<<<dim3(512, 1), 256, 0, stream>>>(Hb, Wm1b, m1b2, A1f, A1b,
                                                  A1f, 128, 512, 14);
    // block 2
    gemm_bf16_k<<<dim3(512, 3), 256, 0, stream>>>(A1b, Wq2, qkv2_b, nullptr, QKVb,
                                                  nullptr, 384, 128, 8);
    v2t_build_k<<<512, 256, 0, stream>>>(QKVb, V2T);
    attn2_mfma_k<<<512, 256, 0, stream>>>(QKVb, V2T, A1f, A1b);
    gemm_bf16_k<<<dim3(512, 4), 256, 0, stream>>>(A1b, Wm2a, m2b1, nullptr, Hb,
                                                  nullptr, 512, 128, 9);
    gemm_bf16_k<<<dim3(512, 1), 256, 0, stream>>>(Hb, Wm2b, m2b2, A1f, A1b,
                                                  A1f, 128, 512, 14);
    // GX = Wx@A1 + bh (bf16, token order)
    gemm_bf16_k<<<dim3(512, 4), 256, 0, stream>>>(A1b, Wwx, bh, nullptr, GXb,
                                                  nullptr, 512, 128, 8);
    // fused LSTM
    lstm_fused_k<<<256, 256, 0, stream>>>(Wwh, GXb, H0b, Cst, HSW);

    // outputs: hs, hf (= hs[15]), Cf
    out_gather_k<<<dim3(64, 4, 16), 256, 0, stream>>>(HSW, out);
    out_gather_k<<<dim3(64, 4, 1), 256, 0, stream>>>(HSW + 15*524288, out + 8388608);
    out_gather_k<<<dim3(64, 4, 1), 256, 0, stream>>>(Cst, out + 8912896);
}

// Round 5
// 921.750 us; speedup vs baseline: 2.1080x; 1.0336x over previous
//
#include <hip/hip_runtime.h>
#include <math.h>

typedef unsigned short u16;
typedef unsigned int   u32;
typedef __attribute__((ext_vector_type(8))) short s16x8;   // 8 bf16 (4 VGPR)
typedef __attribute__((ext_vector_type(4))) float f32x4;

// ---------------- helpers ---------------------------------------------------
__device__ __forceinline__ u16 f2bf(float f) {
    union { float f; u32 u; } a; a.f = f;
    return (u16)((a.u + 0x7fffu + ((a.u >> 16) & 1u)) >> 16);
}
__device__ __forceinline__ float bf2f(u16 h) {
    union { u32 u; float f; } a; a.u = ((u32)h) << 16; return a.f;
}
__device__ __forceinline__ float bflo(u32 u){ union{u32 i;float f;} a; a.i = u<<16; return a.f; }
__device__ __forceinline__ float bfhi(u32 u){ union{u32 i;float f;} a; a.i = u & 0xffff0000u; return a.f; }

__device__ __forceinline__ u32 cvtpk_bf16(float lo, float hi) {
    u32 r;
    asm("v_cvt_pk_bf16_f32 %0, %1, %2" : "=v"(r) : "v"(lo), "v"(hi));
    return r;
}

__device__ __forceinline__ float tanh_fast(float x) {
    float xc = fminf(fmaxf(x, -15.f), 15.f);
    float e = __expf(2.f * xc);
    return (e - 1.f) * __frcp_rn(e + 1.f);
}
__device__ __forceinline__ float erf_fast(float x) {
    float ax = fabsf(x);
    float t = __frcp_rn(fmaf(0.3275911f, ax, 1.f));
    float poly = t*(0.254829592f + t*(-0.284496736f + t*(1.421413741f +
                 t*(-1.453152027f + t*1.061405429f))));
    float y = 1.f - poly * __expf(-ax*ax);
    return copysignf(y, x);
}
__device__ __forceinline__ float gelu_fast(float v) {
    return v * 0.5f * (1.f + erf_fast(v * 0.70710678118654752440f));
}

__device__ __forceinline__ void gload16(const void* g, void* l) {
    __builtin_amdgcn_global_load_lds(
        (const __attribute__((address_space(1))) void*)g,
        (__attribute__((address_space(3))) void*)l, 16, 0, 0);
}

// ---------------- bf16 MFMA GEMM (K multiple of 64): conv only now ---------
// flags: 1 gelu, 2 res f32, 4 write Cf, 8 write Cb, 16 res bf16.
__global__ __launch_bounds__(256) void gemm_bf16_k(
    const u16* __restrict__ A, const u16* __restrict__ B,
    const float* __restrict__ bias, float* __restrict__ Cf,
    u16* __restrict__ Cb, const void* __restrict__ Res,
    int N, int K, int flags)
{
    __shared__ u16 As[128 * 64];
    __shared__ u16 Bs[128 * 64];
    const int tid = threadIdx.x;
    const int w = tid >> 6, lane = tid & 63;
    const int wr = w >> 1, wc = w & 1;
    const int t0 = blockIdx.x * 128, n0 = blockIdx.y * 128;
    const int ns = K >> 6;
    const int rsub = lane >> 3, ssub = lane & 7;

    f32x4 acc[4][4];
#pragma unroll
    for (int m = 0; m < 4; ++m)
#pragma unroll
        for (int n = 0; n < 4; ++n) acc[m][n] = (f32x4){0.f,0.f,0.f,0.f};

    const u16* Abase = A + (size_t)t0 * K;
    const u16* Bbase = B + (size_t)n0 * K;

    for (int s = 0; s < ns; ++s) {
#pragma unroll
        for (int r = 0; r < 4; ++r) {
            int row = r*32 + w*8 + rsub;
            int c16 = ssub ^ (row & 7);
            gload16(Abase + (size_t)row * K + s*64 + c16*8, As + (r*32 + w*8)*64);
        }
#pragma unroll
        for (int r = 0; r < 4; ++r) {
            int row = r*32 + w*8 + rsub;
            int c16 = ssub ^ (row & 7);
            gload16(Bbase + (size_t)row * K + s*64 + c16*8, Bs + (r*32 + w*8)*64);
        }
        __syncthreads();

#pragma unroll
        for (int kk = 0; kk < 2; ++kk) {
            s16x8 av[4], bv[4];
#pragma unroll
            for (int m = 0; m < 4; ++m) {
                int ra = wr*64 + m*16 + (lane & 15);
                int ca = (kk*4 + (lane >> 4)) ^ (ra & 7);
                av[m] = *(const s16x8*)&As[ra*64 + ca*8];
                int rb = wc*64 + m*16 + (lane & 15);
                int cb2 = (kk*4 + (lane >> 4)) ^ (rb & 7);
                bv[m] = *(const s16x8*)&Bs[rb*64 + cb2*8];
            }
#pragma unroll
            for (int m = 0; m < 4; ++m)
#pragma unroll
                for (int n = 0; n < 4; ++n)
                    acc[m][n] = __builtin_amdgcn_mfma_f32_16x16x32_bf16(
                        av[m], bv[n], acc[m][n], 0, 0, 0);
        }
        __syncthreads();
    }

#pragma unroll
    for (int n = 0; n < 4; ++n) {
        int col = n0 + wc*64 + n*16 + (lane & 15);
        float bv = bias ? bias[col] : 0.f;
#pragma unroll
        for (int m = 0; m < 4; ++m) {
            int row0 = t0 + wr*64 + m*16 + (lane >> 4)*4;
#pragma unroll
            for (int j = 0; j < 4; ++j) {
                size_t off = (size_t)(row0 + j) * N + col;
                float v = acc[m][n][j] + bv;
                if (flags & 1)  v = gelu_fast(v);
                if (flags & 2)  v += ((const float*)Res)[off];
                if (flags & 16) v += bf2f(((const u16*)Res)[off]);
                if (flags & 4)  Cf[off] = v;
                if (flags & 8)  Cb[off] = f2bf(v);
            }
        }
    }
}

// ---------------- K=128 GEMM: stage A once, weights from L2, one barrier ---
// C[t][n] = sum_k A[t][k]*W[n][k] + bias[n], bf16 out. N mult of 128.
__global__ __launch_bounds__(256) void gemm128_k(
    const u16* __restrict__ A, const u16* __restrict__ W,
    const float* __restrict__ bias, u16* __restrict__ Cb, int N)
{
    __shared__ u16 As[128 * 128];       // 32 KB, 16 chunks/row, chunk^=(row&7)
    const int tid = threadIdx.x;
    const int w = tid >> 6, lane = tid & 63;
    const int wr = w >> 1, wc = w & 1;
    const int t0 = blockIdx.x * 128, n0 = blockIdx.y * 128;
    const int lq = lane & 15, g = lane >> 4;

    // weight B-frags straight from L2 (issued before barrier)
    s16x8 wv[4][4];
#pragma unroll
    for (int ks = 0; ks < 4; ++ks)
#pragma unroll
        for (int n = 0; n < 4; ++n) {
            int row = n0 + wc*64 + n*16 + lq;
            wv[ks][n] = *(const s16x8*)(W + (size_t)row*128 + ks*32 + g*8);
        }
    // stage A tile (pre-swizzled source, linear LDS dest)
    {
        int rsub = lane >> 4, csub = lane & 15;
#pragma unroll
        for (int r = 0; r < 8; ++r) {
            int row = r*16 + w*4 + rsub;
            gload16(A + (size_t)(t0 + row)*128 + ((csub ^ (row & 7))*8),
                    As + (r*16 + w*4)*128);
        }
    }
    f32x4 acc[4][4];
#pragma unroll
    for (int m = 0; m < 4; ++m)
#pragma unroll
        for (int n = 0; n < 4; ++n) acc[m][n] = (f32x4){0.f,0.f,0.f,0.f};
    __syncthreads();

#pragma unroll
    for (int ks = 0; ks < 4; ++ks) {
        s16x8 av[4];
#pragma unroll
        for (int m = 0; m < 4; ++m) {
            int row = wr*64 + m*16 + lq;
            av[m] = *(const s16x8*)&As[row*128 + (((ks*4 + g) ^ (row & 7))*8)];
        }
#pragma unroll
        for (int m = 0; m < 4; ++m)
#pragma unroll
            for (int n = 0; n < 4; ++n)
                acc[m][n] = __builtin_amdgcn_mfma_f32_16x16x32_bf16(
                    av[m], wv[ks][n], acc[m][n], 0, 0, 0);
    }
#pragma unroll
    for (int n = 0; n < 4; ++n) {
        int col = n0 + wc*64 + n*16 + lq;
        float bv = bias[col];
#pragma unroll
        for (int m = 0; m < 4; ++m) {
            int row0 = t0 + wr*64 + m*16 + g*4;
#pragma unroll
            for (int j = 0; j < 4; ++j)
                Cb[(size_t)(row0 + j)*N + col] = f2bf(acc[m][n][j] + bv);
        }
    }
}

// ---------------- fused MLP: gelu(A@W1^T+b1)@W2^T + b2 + res ---------------
// Stage-1 swapped (H^T = W1*A) so gelu is lane-local; redistribute via
// cvt_pk+shfl (attn2 pattern); stage-2 against W2 from L2.
__global__ __launch_bounds__(256) void mlp_fused_k(
    const u16* __restrict__ Ab, const u16* __restrict__ W1,
    const float* __restrict__ b1, const u16* __restrict__ W2,
    const float* __restrict__ b2, float* __restrict__ A1f,
    u16* __restrict__ A1b)
{
    __shared__ u16 As[128 * 128];       // 32 KB
    const int tid = threadIdx.x;
    const int w = tid >> 6, lane = tid & 63;
    const int t0 = blockIdx.x * 128;
    const int lq = lane & 15, g = lane >> 4;

    {
        int rsub = lane >> 4, csub = lane & 15;
#pragma unroll
        for (int r = 0; r < 8; ++r) {
            int row = r*16 + w*4 + rsub;
            gload16(Ab + (size_t)(t0 + row)*128 + ((csub ^ (row & 7))*8),
                    As + (r*16 + w*4)*128);
        }
    }
    f32x4 acc2[2][8];
#pragma unroll
    for (int m = 0; m < 2; ++m)
#pragma unroll
        for (int n = 0; n < 8; ++n) acc2[m][n] = (f32x4){0.f,0.f,0.f,0.f};
    __syncthreads();

    for (int hc = 0; hc < 4; ++hc) {
        // stage 1: Hacc^T[hid][tok] for this 128-hid chunk
        f32x4 acc1[8][2];
#pragma unroll
        for (int ht = 0; ht < 8; ++ht)
#pragma unroll
            for (int m = 0; m < 2; ++m) acc1[ht][m] = (f32x4){0.f,0.f,0.f,0.f};
#pragma unroll
        for (int ks = 0; ks < 4; ++ks) {
            s16x8 bt[2];
#pragma unroll
            for (int m = 0; m < 2; ++m) {
                int row = w*32 + m*16 + lq;
                bt[m] = *(const s16x8*)&As[row*128 + (((ks*4 + g) ^ (row & 7))*8)];
            }
#pragma unroll
            for (int ht = 0; ht < 8; ++ht) {
                s16x8 af = *(const s16x8*)(W1 + (size_t)(hc*128 + ht*16 + lq)*128
                                           + ks*32 + g*8);
#pragma unroll
                for (int m = 0; m < 2; ++m)
                    acc1[ht][m] = __builtin_amdgcn_mfma_f32_16x16x32_bf16(
                        af, bt[m], acc1[ht][m], 0, 0, 0);
            }
        }
        // bias + gelu (value at hid = hc*128 + ht*16 + g*4 + j, tok = lq)
#pragma unroll
        for (int ht = 0; ht < 8; ++ht) {
            float4 bv = *(const float4*)(b1 + hc*128 + ht*16 + g*4);
            const float* bvp = (const float*)&bv;
#pragma unroll
            for (int m = 0; m < 2; ++m)
#pragma unroll
                for (int j = 0; j < 4; ++j)
                    acc1[ht][m][j] = gelu_fast(acc1[ht][m][j] + bvp[j]);
        }
        // redistribute -> P A-frags, then stage-2 MFMA against W2
#pragma unroll
        for (int kk = 0; kk < 4; ++kk) {
            s16x8 paf[2];
#pragma unroll
            for (int m = 0; m < 2; ++m) {
                u32 a0 = cvtpk_bf16(acc1[2*kk][m][0],   acc1[2*kk][m][1]);
                u32 a1 = cvtpk_bf16(acc1[2*kk][m][2],   acc1[2*kk][m][3]);
                u32 c0 = cvtpk_bf16(acc1[2*kk+1][m][0], acc1[2*kk+1][m][1]);
                u32 c1 = cvtpk_bf16(acc1[2*kk+1][m][2], acc1[2*kk+1][m][3]);
                int s0 = lq + ((g & 1) << 5);
                int s1 = s0 + 16;
                u32 xa0 = __shfl((int)a0, s0), xc0 = __shfl((int)c0, s0);
                u32 xa1 = __shfl((int)a1, s0), xc1 = __shfl((int)c1, s0);
                u32 xa2 = __shfl((int)a0, s1), xc2 = __shfl((int)c0, s1);
                u32 xa3 = __shfl((int)a1, s1), xc3 = __shfl((int)c1, s1);
                union { u32 u[4]; s16x8 v; } pu;
                bool hi = (g >= 2);
                pu.u[0] = hi ? xc0 : xa0;
                pu.u[1] = hi ? xc1 : xa1;
                pu.u[2] = hi ? xc2 : xa2;
                pu.u[3] = hi ? xc3 : xa3;
                paf[m] = pu.v;
            }
#pragma unroll
            for (int no = 0; no < 8; ++no) {
                s16x8 wv2 = *(const s16x8*)(W2 + (size_t)(no*16 + lq)*512
                                            + hc*128 + kk*32 + g*8);
#pragma unroll
                for (int m = 0; m < 2; ++m)
                    acc2[m][no] = __builtin_amdgcn_mfma_f32_16x16x32_bf16(
                        paf[m], wv2, acc2[m][no], 0, 0, 0);
            }
        }
    }
    // epilogue: C rows tok = w*32 + m*16 + g*4 + j, cols o = no*16 + lq
#pragma unroll
    for (int no = 0; no < 8; ++no) {
        float bv = b2[no*16 + lq];
#pragma unroll
        for (int m = 0; m < 2; ++m) {
            int row0 = t0 + w*32 + m*16 + g*4;
#pragma unroll
            for (int j = 0; j < 4; ++j) {
                size_t off = (size_t)(row0 + j)*128 + no*16 + lq;
                float v = acc2[m][no][j] + bv + A1f[off];
                A1f[off] = v;
                A1b[off] = f2bf(v);
            }
        }
    }
}

// ---------------- XA builder: x NCHW -> token-order [65536][512] bf16 ------
__global__ __launch_bounds__(256) void xa_build_k(const float* __restrict__ x,
                                                  u16* __restrict__ XA)
{
    __shared__ float tile[32][2][129];
    const int y = blockIdx.x, cc = blockIdx.y, b = blockIdx.z;
    const int tid = threadIdx.x;
    {
        int c_i = tid >> 3, rem = tid & 7;
        int yy = rem >> 2, qx = rem & 3;
        const float* p = x + (((size_t)(b*128 + cc*32 + c_i) * 128) + (2*y + yy)) * 128 + qx*32;
#pragma unroll
        for (int e = 0; e < 8; ++e) {
            float4 v = ((const float4*)p)[e];
            tile[c_i][yy][qx*32 + e*4 + 0] = v.x;
            tile[c_i][yy][qx*32 + e*4 + 1] = v.y;
            tile[c_i][yy][qx*32 + e*4 + 2] = v.z;
            tile[c_i][yy][qx*32 + e*4 + 3] = v.w;
        }
    }
    __syncthreads();
    {
        int xo = tid >> 2, kq = tid & 3;
        int ky = kq >> 1, kx = kq & 1;
        size_t t = (size_t)b*4096 + ((y>>2)*16 + (xo>>2))*16 + (y&3)*4 + (xo&3);
        u16* dst = XA + t*512 + kq*128 + cc*32;
        u32 pk[16];
#pragma unroll
        for (int e = 0; e < 16; ++e) {
            float v0 = tile[2*e  ][ky][2*xo + kx];
            float v1 = tile[2*e+1][ky][2*xo + kx];
            pk[e] = (u32)f2bf(v0) | ((u32)f2bf(v1) << 16);
        }
#pragma unroll
        for (int e = 0; e < 4; ++e)
            ((uint4*)dst)[e] = make_uint4(pk[4*e], pk[4*e+1], pk[4*e+2], pk[4*e+3]);
    }
}

// ---------------- weight convert ------------------------------------------
__global__ void conv_weights_k(const float* __restrict__ conv_w, const float* __restrict__ qkv1_w,
    const float* __restrict__ m1w1, const float* __restrict__ m1w2,
    const float* __restrict__ qkv2_w, const float* __restrict__ m2w1,
    const float* __restrict__ m2w2, const float* __restrict__ wx,
    const float* __restrict__ wh, u16* __restrict__ Wb)
{
    int idx = blockIdx.x * 256 + threadIdx.x;
    if (idx >= 557056) return;
    float v;
    if (idx < 65536) { int o = idx >> 9, k = idx & 511; v = conv_w[((o*128 + (k & 127)) << 2) + (k >> 7)]; }
    else if (idx < 114688) v = qkv1_w[idx - 65536];
    else if (idx < 180224) v = m1w1[idx - 114688];
    else if (idx < 245760) v = m1w2[idx - 180224];
    else if (idx < 294912) v = qkv2_w[idx - 245760];
    else if (idx < 360448) v = m2w1[idx - 294912];
    else if (idx < 425984) v = m2w2[idx - 360448];
    else if (idx < 491520) v = wx[idx - 425984];
    else v = wh[idx - 491520];
    Wb[idx] = f2bf(v);
}

// ---------------- MSA1: 1 wave per window; lane = (r, h, half) -------------
__global__ __launch_bounds__(256) void attn1_k(const u16* __restrict__ QKV,
                                               float* __restrict__ A1f,
                                               u16* __restrict__ A1b)
{
    int bx = blockIdx.x;                 // 1024
    int b = bx >> 6, g4 = bx & 63;
    int w = threadIdx.x >> 6, lane = threadIdx.x & 63;
    int g = g4*4 + w;
    int r = lane & 15, h = (lane >> 4) & 1, half = lane >> 5;
    size_t tb = ((size_t)(b*256 + g)) * 16;
    float qr[32];
    {
        const uint4* qp = (const uint4*)(QKV + (tb + r)*384 + h*64 + half*32);
#pragma unroll
        for (int i = 0; i < 4; ++i) {
            uint4 u = qp[i];
            qr[8*i+0]=bflo(u.x); qr[8*i+1]=bfhi(u.x); qr[8*i+2]=bflo(u.y); qr[8*i+3]=bfhi(u.y);
            qr[8*i+4]=bflo(u.z); qr[8*i+5]=bfhi(u.z); qr[8*i+6]=bflo(u.w); qr[8*i+7]=bfhi(u.w);
        }
    }
    float sc[16]; float mx = -1e30f;
#pragma unroll
    for (int k = 0; k < 16; ++k) {
        const uint4* kp = (const uint4*)(QKV + (tb + k)*384 + 128 + h*64 + half*32);
        float s0 = 0.f, s1 = 0.f, s2 = 0.f, s3 = 0.f;
#pragma unroll
        for (int i = 0; i < 4; ++i) {
            uint4 u = kp[i];
            float* sp = (i == 0) ? &s0 : (i == 1) ? &s1 : (i == 2) ? &s2 : &s3;
            float s = *sp;
            s = fmaf(qr[8*i+0], bflo(u.x), s); s = fmaf(qr[8*i+1], bfhi(u.x), s);
            s = fmaf(qr[8*i+2], bflo(u.y), s); s = fmaf(qr[8*i+3], bfhi(u.y), s);
            s = fmaf(qr[8*i+4], bflo(u.z), s); s = fmaf(qr[8*i+5], bfhi(u.z), s);
            s = fmaf(qr[8*i+6], bflo(u.w), s); s = fmaf(qr[8*i+7], bfhi(u.w), s);
            *sp = s;
        }
        float s = (s0 + s1) + (s2 + s3);
        s += __shfl_xor(s, 32);
        sc[k] = s * 0.08838834764831845f;
        mx = fmaxf(mx, sc[k]);
    }
    float sum = 0.f;
#pragma unroll
    for (int k = 0; k < 16; ++k) { sc[k] = __expf(sc[k] - mx); sum += sc[k]; }
    float inv = __frcp_rn(sum);
    float outv[32] = {};
#pragma unroll
    for (int k = 0; k < 16; ++k) {
        float p = sc[k] * inv;
        const uint4* vp = (const uint4*)(QKV + (tb + k)*384 + 256 + h*64 + half*32);
#pragma unroll
        for (int i = 0; i < 4; ++i) {
            uint4 u = vp[i];
            outv[8*i+0] = fmaf(p, bflo(u.x), outv[8*i+0]); outv[8*i+1] = fmaf(p, bfhi(u.x), outv[8*i+1]);
            outv[8*i+2] = fmaf(p, bflo(u.y), outv[8*i+2]); outv[8*i+3] = fmaf(p, bfhi(u.y), outv[8*i+3]);
            outv[8*i+4] = fmaf(p, bflo(u.z), outv[8*i+4]); outv[8*i+5] = fmaf(p, bfhi(u.z), outv[8*i+5]);
            outv[8*i+6] = fmaf(p, bflo(u.w), outv[8*i+6]); outv[8*i+7] = fmaf(p, bfhi(u.w), outv[8*i+7]);
        }
    }
    float* dst = A1f + (tb + r)*128 + h*64 + half*32;
    u16*  dstb = A1b + (tb + r)*128 + h*64 + half*32;
#pragma unroll
    for (int i = 0; i < 8; ++i) {
        float4 o = ((float4*)dst)[i];
        o.x += outv[4*i]; o.y += outv[4*i+1]; o.z += outv[4*i+2]; o.w += outv[4*i+3];
        ((float4*)dst)[i] = o;
        u32 p0 = (u32)f2bf(o.x) | ((u32)f2bf(o.y) << 16);
        u32 p1 = (u32)f2bf(o.z) | ((u32)f2bf(o.w) << 16);
        ((uint2*)dstb)[i] = make_uint2(p0, p1);
    }
}

// ---------------- V2T builder: QKV V-part -> V2T[b][l][h][d][g] bf16 -------
__global__ __launch_bounds__(256) void v2t_build_k(const u16* __restrict__ QKV,
                                                   u16* __restrict__ V2T)
{
    __shared__ u16 T[256 * 64];          // [g][d], chunk-swizzled e^=(g>>3)&7
    int bx = blockIdx.x;                 // 512 = b(16) x l(16) x h(2)
    int b = bx >> 5, l = (bx >> 1) & 15, h = bx & 1;
    int tid = threadIdx.x;
    {
        int g = tid;
        const uint4* src = (const uint4*)(QKV + (((size_t)(b*256 + g)*16 + l)*384) + 256 + h*64);
#pragma unroll
        for (int e = 0; e < 8; ++e) {
            uint4 u = src[e];
            int ep = e ^ ((g >> 3) & 7);
            *(uint4*)((char*)T + g*128 + ep*16) = u;
        }
    }
    __syncthreads();
    u16* dstb = V2T + ((size_t)(((b*16 + l)*2 + h)*64))*256;
#pragma unroll
    for (int rr = 0; rr < 8; ++rr) {
        int R = rr*256 + tid;            // 0..2047
        int d = R >> 5, ck = R & 31;     // chunk of 8 g
        union { u16 s[8]; uint4 v; } o;
#pragma unroll
        for (int j = 0; j < 8; ++j) {
            int g = ck*8 + j;
            int chunk = (d >> 3) ^ ((g >> 3) & 7);
            o.s[j] = *(const u16*)((const char*)T + g*128 + chunk*16 + (d & 7)*2);
        }
        *(uint4*)(dstb + (size_t)d*256 + ck*8) = o.v;
    }
}

// ---------------- MSA2: MFMA flash attention over 256 windows --------------
__global__ __launch_bounds__(256, 2) void attn2_mfma_k(
    const u16* __restrict__ QKV, const u16* __restrict__ V2T,
    float* __restrict__ A1f, u16* __restrict__ A1b)
{
    __shared__ u16 Ksw[256 * 64];        // 32 KB
    __shared__ u16 Vtw[64 * 256];        // 32 KB
    const int bx = blockIdx.x;           // 512
    const int b = bx >> 5, l = (bx >> 1) & 15, h = bx & 1;
    const int tid = threadIdx.x;
    const int w = tid >> 6, lane = tid & 63;
    const int lq = lane & 15, g = lane >> 4;

    {
        int rsub = lane >> 3, ssub = lane & 7;
#pragma unroll
        for (int r = 0; r < 8; ++r) {
            int row = r*32 + w*8 + rsub;
            size_t t = ((size_t)(b*256 + row))*16 + l;
            gload16(QKV + t*384 + 128 + h*64 + ((ssub ^ (row & 7))*8),
                    Ksw + (r*32 + w*8)*64);
        }
    }
    {
        int rsub = lane >> 5, ssub = lane & 31;
        const u16* vb = V2T + ((size_t)(((b*16 + l)*2 + h)*64))*256;
#pragma unroll
        for (int r = 0; r < 8; ++r) {
            int row = r*8 + w*2 + rsub;
            gload16(vb + (size_t)row*256 + ((ssub ^ (row & 7))*8),
                    Vtw + (r*8 + w*2)*256);
        }
    }
    s16x8 qf[4][2];
#pragma unroll
    for (int nq = 0; nq < 4; ++nq) {
        int q = w*64 + nq*16 + lq;
        size_t t = ((size_t)(b*256 + q))*16 + l;
#pragma unroll
        for (int kf = 0; kf < 2; ++kf)
            qf[nq][kf] = *(const s16x8*)(QKV + t*384 + h*64 + kf*32 + g*8);
    }
    __syncthreads();

    f32x4 oacc[4][4];
#pragma unroll
    for (int m = 0; m < 4; ++m)
#pragma unroll
        for (int n = 0; n < 4; ++n) oacc[m][n] = (f32x4){0.f,0.f,0.f,0.f};
    float mrow[4] = {-1e30f,-1e30f,-1e30f,-1e30f};
    float lsum[4] = {0.f,0.f,0.f,0.f};
    const float scale = 0.08838834764831845f;

    for (int kc4 = 0; kc4 < 4; ++kc4) {
        f32x4 skt[4][4];
#pragma unroll
        for (int m = 0; m < 4; ++m)
#pragma unroll
            for (int n = 0; n < 4; ++n) skt[m][n] = (f32x4){0.f,0.f,0.f,0.f};
#pragma unroll
        for (int mk = 0; mk < 4; ++mk) {
            int row = kc4*64 + mk*16 + lq;
#pragma unroll
            for (int kf = 0; kf < 2; ++kf) {
                s16x8 kfr = *(const s16x8*)&Ksw[row*64 + (((kf*4 + g) ^ (row & 7))*8)];
#pragma unroll
                for (int nq = 0; nq < 4; ++nq)
                    skt[mk][nq] = __builtin_amdgcn_mfma_f32_16x16x32_bf16(
                        kfr, qf[nq][kf], skt[mk][nq], 0, 0, 0);
            }
        }
        float corr[4];
#pragma unroll
        for (int nq = 0; nq < 4; ++nq) {
            float mx = -1e30f;
#pragma unroll
            for (int mk = 0; mk < 4; ++mk)
#pragma unroll
                for (int j = 0; j < 4; ++j) {
                    skt[mk][nq][j] *= scale;
                    mx = fmaxf(mx, skt[mk][nq][j]);
                }
            mx = fmaxf(mx, __shfl_xor(mx, 16));
            mx = fmaxf(mx, __shfl_xor(mx, 32));
            float nm = fmaxf(mrow[nq], mx);
            corr[nq] = __expf(mrow[nq] - nm);
            mrow[nq] = nm;
        }
#pragma unroll
        for (int nq = 0; nq < 4; ++nq) {
            float ps = 0.f;
#pragma unroll
            for (int mk = 0; mk < 4; ++mk)
#pragma unroll
                for (int j = 0; j < 4; ++j) {
                    float p = __expf(skt[mk][nq][j] - mrow[nq]);
                    skt[mk][nq][j] = p; ps += p;
                }
            ps += __shfl_xor(ps, 16);
            ps += __shfl_xor(ps, 32);
            lsum[nq] = lsum[nq]*corr[nq] + ps;
        }
#pragma unroll
        for (int mq = 0; mq < 4; ++mq)
#pragma unroll
            for (int j = 0; j < 4; ++j) {
                float cO = __shfl(corr[mq], 4*g + j);
#pragma unroll
                for (int nd = 0; nd < 4; ++nd) oacc[mq][nd][j] *= cO;
            }
#pragma unroll
        for (int c = 0; c < 2; ++c) {
            s16x8 paf[4];
#pragma unroll
            for (int mq = 0; mq < 4; ++mq) {
                u32 a0 = cvtpk_bf16(skt[2*c][mq][0],   skt[2*c][mq][1]);
                u32 a1 = cvtpk_bf16(skt[2*c][mq][2],   skt[2*c][mq][3]);
                u32 b0 = cvtpk_bf16(skt[2*c+1][mq][0], skt[2*c+1][mq][1]);
                u32 b1 = cvtpk_bf16(skt[2*c+1][mq][2], skt[2*c+1][mq][3]);
                int s0 = lq + ((g & 1) << 5);
                int s1 = s0 + 16;
                u32 xa0 = __shfl((int)a0, s0), xb0 = __shfl((int)b0, s0);
                u32 xa1 = __shfl((int)a1, s0), xb1 = __shfl((int)b1, s0);
                u32 xa2 = __shfl((int)a0, s1), xb2 = __shfl((int)b0, s1);
                u32 xa3 = __shfl((int)a1, s1), xb3 = __shfl((int)b1, s1);
                union { u32 u[4]; s16x8 v; } pu;
                bool hi = (g >= 2);
                pu.u[0] = hi ? (u32)xb0 : (u32)xa0;
                pu.u[1] = hi ? (u32)xb1 : (u32)xa1;
                pu.u[2] = hi ? (u32)xb2 : (u32)xa2;
                pu.u[3] = hi ? (u32)xb3 : (u32)xa3;
                paf[mq] = pu.v;
            }
            int kc = kc4*2 + c;
#pragma unroll
            for (int nd = 0; nd < 4; ++nd) {
                int d = nd*16 + lq;
                s16x8 vf = *(const s16x8*)((const char*)Vtw +
                            d*512 + (((kc*4 + g) ^ (d & 7))*16));
#pragma unroll
                for (int mq = 0; mq < 4; ++mq)
                    oacc[mq][nd] = __builtin_amdgcn_mfma_f32_16x16x32_bf16(
                        paf[mq], vf, oacc[mq][nd], 0, 0, 0);
            }
        }
    }
    float linv[4];
#pragma unroll
    for (int nq = 0; nq < 4; ++nq) linv[nq] = __frcp_rn(lsum[nq]);
#pragma unroll
    for (int mq = 0; mq < 4; ++mq)
#pragma unroll
        for (int j = 0; j < 4; ++j) {
            float inv = __shfl(linv[mq], 4*g + j);
            size_t t = ((size_t)(b*256 + w*64 + mq*16 + 4*g + j))*16 + l;
#pragma unroll
            for (int nd = 0; nd < 4; ++nd) {
                size_t off = t*128 + h*64 + nd*16 + lq;
                float v = A1f[off] + oacc[mq][nd][j]*inv;
                A1f[off] = v;
                A1b[off] = f2bf(v);
            }
        }
}

// ---------------- LSTM init: h0/c0 NCHW -> token-order states --------------
__global__ void lstm_init_k(const float* __restrict__ h0, const float* __restrict__ c0,
                            u16* __restrict__ H0b, float* __restrict__ Cst)
{
    int idx = blockIdx.x * 256 + threadIdx.x;     // 32768
    int t = idx >> 3, q = idx & 7;
    int g = t >> 4, l = t & 15;
    int y = (g >> 4)*4 + (l >> 2);
    int x = (g & 15)*4 + (l & 3);
    int hw = y*64 + x;
    u32 pk[8]; float cs[16];
#pragma unroll
    for (int e = 0; e < 16; ++e) {
        int c = q*16 + e;
        float hv = h0[(size_t)c*4096 + hw];
        cs[e] = c0[(size_t)c*4096 + hw];
        if (e & 1) pk[e>>1] |= ((u32)f2bf(hv)) << 16;
        else       pk[e>>1]  = (u32)f2bf(hv);
    }
    u16* hd = H0b + (size_t)t*128 + q*16;
    ((uint4*)hd)[0] = make_uint4(pk[0], pk[1], pk[2], pk[3]);
    ((uint4*)hd)[1] = make_uint4(pk[4], pk[5], pk[6], pk[7]);
    float* cd = Cst + (size_t)t*128 + q*16;
#pragma unroll
    for (int e = 0; e < 4; ++e)
        ((float4*)cd)[e] = make_float4(cs[4*e], cs[4*e+1], cs[4*e+2], cs[4*e+3]);
}

// ---------------- fused ConvLSTM: all 16 steps in one kernel ---------------
__global__ __launch_bounds__(256, 1) void lstm_fused_k(
    const u16* __restrict__ Whb, const u16* __restrict__ GXb,
    const u16* __restrict__ H0b, float* __restrict__ Cst,
    float* __restrict__ HSW)
{
    __shared__ u16  Hl[16 * 128];
    __shared__ float Gl[16 * 512];
    __shared__ u16  GXl[2][8192];

    const int tid = threadIdx.x;
    const int w = tid >> 6, lane = tid & 63;
    const int t0 = blockIdx.x * 16;
    const int lr = lane & 15, lg = lane >> 4;

    s16x8 wf[8][4];
#pragma unroll
    for (int nt = 0; nt < 8; ++nt)
#pragma unroll
        for (int ks = 0; ks < 4; ++ks)
            wf[nt][ks] = *(const s16x8*)(Whb + (size_t)(w*128 + nt*16 + lr)*128
                                         + ks*32 + lg*8);
    float cst[8];
    {
        const float4* cp = (const float4*)(Cst + (size_t)(t0 + lr)*128 + 32*w + lg*8);
        float4 c0v = cp[0], c1v = cp[1];
        cst[0]=c0v.x; cst[1]=c0v.y; cst[2]=c0v.z; cst[3]=c0v.w;
        cst[4]=c1v.x; cst[5]=c1v.y; cst[6]=c1v.z; cst[7]=c1v.w;
    }
    {
        int row = tid >> 4, seg = tid & 15;
        uint4 hv = *(const uint4*)(H0b + (size_t)(t0 + row)*128 + seg*8);
        int db = row*256 + ((seg*16) ^ ((row & 7) << 4));
        *(uint4*)((char*)Hl + db) = hv;
    }
    {
        const u16* src = GXb + (size_t)t0 * 512;
#pragma unroll
        for (int r4 = 0; r4 < 4; ++r4)
            gload16(src + w*2048 + r4*512 + lane*8, &GXl[0][w*2048 + r4*512]);
    }
    asm volatile("s_waitcnt vmcnt(0)" ::: "memory");
    __syncthreads();

    for (int s = 0; s < 16; ++s) {
        const int cur = s & 1;
        if (s < 15) {
            const u16* src = GXb + ((size_t)((s + 1)*4096 + t0))*512;
#pragma unroll
            for (int r4 = 0; r4 < 4; ++r4)
                gload16(src + w*2048 + r4*512 + lane*8, &GXl[cur ^ 1][w*2048 + r4*512]);
        }
        s16x8 af[4];
#pragma unroll
        for (int ks = 0; ks < 4; ++ks) {
            int bo = lr*256 + ((ks*64 + lg*16) ^ ((lr & 7) << 4));
            af[ks] = *(const s16x8*)((const char*)Hl + bo);
        }
        f32x4 acc[8];
        {
            const u16* gx = &GXl[cur][0];
#pragma unroll
            for (int nt = 0; nt < 8; ++nt)
#pragma unroll
                for (int j = 0; j < 4; ++j)
                    acc[nt][j] = bf2f(gx[(lg*4 + j)*512 + 128*w + nt*16 + lr]);
        }
#pragma unroll
        for (int ks = 0; ks < 4; ++ks)
#pragma unroll
            for (int nt = 0; nt < 8; ++nt)
                acc[nt] = __builtin_amdgcn_mfma_f32_16x16x32_bf16(
                    af[ks], wf[nt][ks], acc[nt], 0, 0, 0);
        if (w != 2) {
#pragma unroll
            for (int j = 0; j < 4; ++j) {
                float mx = acc[0][j];
#pragma unroll
                for (int nt = 1; nt < 8; ++nt) mx = fmaxf(mx, acc[nt][j]);
#pragma unroll
                for (int msk = 1; msk < 16; msk <<= 1) mx = fmaxf(mx, __shfl_xor(mx, msk));
                float ssum = 0.f;
#pragma unroll
                for (int nt = 0; nt < 8; ++nt) {
                    float e = __expf(acc[nt][j] - mx);
                    acc[nt][j] = e; ssum += e;
                }
#pragma unroll
                for (int msk = 1; msk < 16; msk <<= 1) ssum += __shfl_xor(ssum, msk);
                float inv = __frcp_rn(ssum);
#pragma unroll
                for (int nt = 0; nt < 8; ++nt) acc[nt][j] *= inv;
            }
        } else {
#pragma unroll
            for (int nt = 0; nt < 8; ++nt)
#pragma unroll
                for (int j = 0; j < 4; ++j)
                    acc[nt][j] = tanh_fast(acc[nt][j]);
        }
#pragma unroll
        for (int nt = 0; nt < 8; ++nt)
#pragma unroll
            for (int j = 0; j < 4; ++j) {
                int t = lg*4 + j;
                int bo = (t*2048 + (w*128 + nt*16 + lr)*4) ^ ((t & 7) << 5);
                *(float*)((char*)Gl + bo) = acc[nt][j];
            }
        __syncthreads();
        float fv[8], iv[8], sv[8], ov[8];
        {
            int colb = (32*w + lg*8)*4;
#pragma unroll
            for (int g = 0; g < 4; ++g) {
                int bo = (lr*2048 + g*512 + colb) ^ ((lr & 7) << 5);
                float4 a = *(const float4*)((const char*)Gl + bo);
                float4 b2 = *(const float4*)((const char*)Gl + (bo + 16));
                float* dstv = (g == 0) ? fv : (g == 1) ? iv : (g == 2) ? sv : ov;
                dstv[0]=a.x; dstv[1]=a.y; dstv[2]=a.z; dstv[3]=a.w;
                dstv[4]=b2.x; dstv[5]=b2.y; dstv[6]=b2.z; dstv[7]=b2.w;
            }
        }
        float hn[8];
#pragma unroll
        for (int j = 0; j < 8; ++j) {
            cst[j] = fmaf(fv[j], cst[j], iv[j] * sv[j]);
            hn[j] = ov[j] * tanh_fast(cst[j]);
        }
        {
            u32 p0 = (u32)f2bf(hn[0]) | ((u32)f2bf(hn[1])<<16);
            u32 p1 = (u32)f2bf(hn[2]) | ((u32)f2bf(hn[3])<<16);
            u32 p2 = (u32)f2bf(hn[4]) | ((u32)f2bf(hn[5])<<16);
            u32 p3 = (u32)f2bf(hn[6]) | ((u32)f2bf(hn[7])<<16);
            int bo = (lr*256 + (32*w + lg*8)*2) ^ ((lr & 7) << 4);
            *(uint4*)((char*)Hl + bo) = make_uint4(p0, p1, p2, p3);
        }
        {
            float* hp = HSW + ((size_t)s*4096 + t0 + lr)*128 + 32*w + lg*8;
            ((float4*)hp)[0] = make_float4(hn[0], hn[1], hn[2], hn[3]);
            ((float4*)hp)[1] = make_float4(hn[4], hn[5], hn[6], hn[7]);
        }
        __syncthreads();
    }
    {
        float* cp = Cst + (size_t)(t0 + lr)*128 + 32*w + lg*8;
        ((float4*)cp)[0] = make_float4(cst[0], cst[1], cst[2], cst[3]);
        ((float4*)cp)[1] = make_float4(cst[4], cst[5], cst[6], cst[7]);
    }
}

// ---------------- output gather: [t][c] token-order -> [c][y][x] -----------
__global__ void out_gather_k(const float* __restrict__ src, float* __restrict__ dst)
{
    __shared__ float tile[32][65];
    int y = blockIdx.x, cc = blockIdx.y, s = blockIdx.z;
    const float* sp = src + (size_t)s*524288;
    float* dp = dst + (size_t)s*524288;
    int tid = threadIdx.x;
    {
        int xi = tid >> 2, cq = tid & 3;
        int t = ((y>>2)*16 + (xi>>2))*16 + (y&3)*4 + (xi&3);
        const float* p = sp + (size_t)t*128 + cc*32 + cq*8;
        float4 a = ((const float4*)p)[0], b2 = ((const float4*)p)[1];
        tile[cq*8+0][xi]=a.x; tile[cq*8+1][xi]=a.y; tile[cq*8+2][xi]=a.z; tile[cq*8+3][xi]=a.w;
        tile[cq*8+4][xi]=b2.x; tile[cq*8+5][xi]=b2.y; tile[cq*8+6][xi]=b2.z; tile[cq*8+7][xi]=b2.w;
    }
    __syncthreads();
    {
        int ci = tid >> 3, xq = tid & 7;
        float* p = dp + (size_t)(cc*32 + ci)*4096 + y*64 + xq*8;
#pragma unroll
        for (int e = 0; e < 8; ++e) p[e] = tile[ci][xq*8 + e];
    }
}

// ---------------------------------------------------------------------------
extern "C" void kernel_launch(void* const* d_in, const int* in_sizes, int n_in,
                              void* d_out, int out_size, void* d_ws, size_t ws_size,
                              hipStream_t stream)
{
    const float* x      = (const float*)d_in[0];
    const float* h0     = (const float*)d_in[1];
    const float* c0     = (const float*)d_in[2];
    const float* conv_w = (const float*)d_in[3];
    const float* conv_b = (const float*)d_in[4];
    const float* qkv1_w = (const float*)d_in[5];
    const float* qkv1_b = (const float*)d_in[6];
    const float* m1w1   = (const float*)d_in[7];
    const float* m1b1   = (const float*)d_in[8];
    const float* m1w2   = (const float*)d_in[9];
    const float* m1b2   = (const float*)d_in[10];
    const float* qkv2_w = (const float*)d_in[11];
    const float* qkv2_b = (const float*)d_in[12];
    const float* m2w1   = (const float*)d_in[13];
    const float* m2b1   = (const float*)d_in[14];
    const float* m2w2   = (const float*)d_in[15];
    const float* m2b2   = (const float*)d_in[16];
    const float* wx     = (const float*)d_in[17];
    const float* wh     = (const float*)d_in[18];
    const float* bh     = (const float*)d_in[19];
    float* out = (float*)d_out;

    char* ws = (char*)d_ws;
    u16*   XAb   = (u16*)(ws);                       // [65536][512] bf16 (reuse)
    u16*   GXb   = (u16*)(ws);                       // [65536][512] bf16 (reuse)
    u16*   QKVb  = (u16*)(ws + 67108864);            // [65536][384] bf16
    float* A1f   = (float*)(ws + 117440512);         // [65536][128] f32
    u16*   A1b   = (u16*)(ws + 150994944);           // [65536][128] bf16
    float* HSW   = (float*)(ws + 167772160);         // [16][4096][128] f32
    u16*   V2T   = (u16*)(ws + 167772160);           // V^T scratch (dead before LSTM)
    float* Cst   = (float*)(ws + 201326592);         // [4096][128] f32
    u16*   H0b   = (u16*)(ws + 203423744);           // [4096][128] bf16
    u16*   Wb    = (u16*)(ws + 212860928);           // 557056 bf16 weights

    const u16* Wconv = Wb;
    const u16* Wq1   = Wb + 65536;
    const u16* Wm1a  = Wb + 114688;
    const u16* Wm1b  = Wb + 180224;
    const u16* Wq2   = Wb + 245760;
    const u16* Wm2a  = Wb + 294912;
    const u16* Wm2b  = Wb + 360448;
    const u16* Wwx   = Wb + 425984;
    const u16* Wwh   = Wb + 491520;

    conv_weights_k<<<2177, 256, 0, stream>>>(conv_w, qkv1_w, m1w1, m1w2, qkv2_w,
                                             m2w1, m2w2, wx, wh, Wb);
    xa_build_k<<<dim3(64, 4, 16), 256, 0, stream>>>(x, XAb);
    lstm_init_k<<<128, 256, 0, stream>>>(h0, c0, H0b, Cst);

    // conv as GEMM -> A1f + A1b
    gemm_bf16_k<<<dim3(512, 1), 256, 0, stream>>>(XAb, Wconv, conv_b, A1f, A1b,
                                                  nullptr, 128, 512, 12);
    // block 1
    gemm128_k<<<dim3(512, 3), 256, 0, stream>>>(A1b, Wq1, qkv1_b, QKVb, 384);
    attn1_k<<<1024, 256, 0, stream>>>(QKVb, A1f, A1b);
    mlp_fused_k<<<512, 256, 0, stream>>>(A1b, Wm1a, m1b1, Wm1b, m1b2, A1f, A1b);
    // block 2
    gemm128_k<<<dim3(512, 3), 256, 0, stream>>>(A1b, Wq2, qkv2_b, QKVb, 384);
    v2t_build_k<<<512, 256, 0, stream>>>(QKVb, V2T);
    attn2_mfma_k<<<512, 256, 0, stream>>>(QKVb, V2T, A1f, A1b);
    mlp_fused_k<<<512, 256, 0, stream>>>(A1b, Wm2a, m2b1, Wm2b, m2b2, A1f, A1b);
    // GX = Wx@A1 + bh (bf16, token order)
    gemm128_k<<<dim3(512, 4), 256, 0, stream>>>(A1b, Wwx, bh, GXb, 512);
    // fused LSTM
    lstm_fused_k<<<256, 256, 0, stream>>>(Wwh, GXb, H0b, Cst, HSW);

    // outputs: hs, hf (= hs[15]), Cf
    out_gather_k<<<dim3(64, 4, 16), 256, 0, stream>>>(HSW, out);
    out_gather_k<<<dim3(64, 4, 1), 256, 0, stream>>>(HSW + 15*524288, out + 8388608);
    out_gather_k<<<dim3(64, 4, 1), 256, 0, stream>>>(Cst, out + 8912896);
}